// Round 1
// 406.302 us; speedup vs baseline: 1.1697x; 1.1697x over previous
//
#include <hip/hip_runtime.h>
#include <stdint.h>

#define N_NODES 100000
#define N_EDGES 1600000
#define D_INF   128
#define D_HID   64
#define D_LAT   32
#define NB      98      // ceil(N_NODES/1024)

typedef __attribute__((ext_vector_type(8))) short bf16x8;
typedef __attribute__((ext_vector_type(4))) float f32x4;

__device__ __forceinline__ unsigned short f2bf(float v) {
  union { float f; unsigned int u; } x; x.f = v;
  unsigned int u = x.u + 0x7FFF + ((x.u >> 16) & 1);   // RNE
  return (unsigned short)(u >> 16);
}
__device__ __forceinline__ float bf2f(unsigned short h) {
  union { unsigned int u; float f; } x; x.u = ((unsigned int)h) << 16;
  return x.f;
}

// ---------------- CSR build ----------------

__global__ void k_zero(int* __restrict__ counts) {
  int i = blockIdx.x * 256 + threadIdx.x;
  if (i < N_NODES) counts[i] = 0;
}

__global__ void k_count(const int* __restrict__ dst, int* __restrict__ counts) {
  int e = blockIdx.x * 256 + threadIdx.x;
  if (e < N_EDGES) atomicAdd(&counts[dst[e]], 1);
}

__global__ void k_blocksum(const int* __restrict__ counts, int* __restrict__ bsums) {
  __shared__ int red[4];
  int base = blockIdx.x * 1024 + threadIdx.x * 4;
  int s = 0;
#pragma unroll
  for (int j = 0; j < 4; j++) { int i = base + j; if (i < N_NODES) s += counts[i]; }
#pragma unroll
  for (int off = 32; off > 0; off >>= 1) s += __shfl_down(s, off, 64);
  if ((threadIdx.x & 63) == 0) red[threadIdx.x >> 6] = s;
  __syncthreads();
  if (threadIdx.x == 0) bsums[blockIdx.x] = red[0] + red[1] + red[2] + red[3];
}

__global__ void k_scanblocks(const int* __restrict__ bsums, int* __restrict__ bbase,
                             int* __restrict__ offsets) {
  __shared__ int sh[128];
  int t = threadIdx.x;
  int v = (t < NB) ? bsums[t] : 0;
  sh[t] = v;
  __syncthreads();
  int incl = v;
#pragma unroll
  for (int off = 1; off < 128; off <<= 1) {
    int x = (t >= off) ? sh[t - off] : 0;
    __syncthreads();
    incl += x;
    sh[t] = incl;
    __syncthreads();
  }
  if (t < NB) bbase[t] = incl - v;
  if (t == NB - 1) offsets[N_NODES] = incl;   // == N_EDGES
}

__global__ void k_scanchunk(const int* __restrict__ counts, const int* __restrict__ bbase,
                            int* __restrict__ offsets, int* __restrict__ cursor,
                            float* __restrict__ dinv) {
  __shared__ int sh[256];
  int b = blockIdx.x, t = threadIdx.x;
  int base = b * 1024 + t * 4;
  int v[4]; int s = 0;
#pragma unroll
  for (int j = 0; j < 4; j++) { v[j] = (base + j < N_NODES) ? counts[base + j] : 0; s += v[j]; }
  sh[t] = s;
  __syncthreads();
  int incl = s;
#pragma unroll
  for (int off = 1; off < 256; off <<= 1) {
    int x = (t >= off) ? sh[t - off] : 0;
    __syncthreads();
    incl += x;
    sh[t] = incl;
    __syncthreads();
  }
  int run = bbase[b] + incl - s;
#pragma unroll
  for (int j = 0; j < 4; j++) {
    int i = base + j;
    if (i < N_NODES) {
      offsets[i] = run;
      cursor[i]  = run;
      dinv[i]    = rsqrtf((float)(v[j] + 1));   // deg = in-count + self-loop
      run += v[j];
    }
  }
}

// Partitioned CSR build (round 5): writes confined to 1.6 MB csr8 slices.
#define BUILD_PARTS 8
#define NODES_PER_PART 12500
#define BUILD_CHUNKS 391   // ceil(400000 int4s / 1024)

__global__ __launch_bounds__(256) void k_build(const int* __restrict__ esrc,
                                               const int* __restrict__ edst,
                                               const float* __restrict__ dinv,
                                               int* __restrict__ cursor,
                                               int2* __restrict__ csr8) {
  int part  = blockIdx.x & (BUILD_PARTS - 1);   // round-robins over XCDs
  int chunk = blockIdx.x >> 3;
  int lo = part * NODES_PER_PART, hi = lo + NODES_PER_PART;
  const int4* s4 = (const int4*)esrc;
  const int4* d4 = (const int4*)edst;
#pragma unroll
  for (int i = 0; i < 4; i++) {
    int idx4 = chunk * 1024 + i * 256 + threadIdx.x;
    if (idx4 < N_EDGES / 4) {
      int4 ss = s4[idx4];
      int4 dd = d4[idx4];
      int sa[4] = {ss.x, ss.y, ss.z, ss.w};
      int da[4] = {dd.x, dd.y, dd.z, dd.w};
#pragma unroll
      for (int j = 0; j < 4; j++) {
        int d = da[j];
        if (d >= lo && d < hi) {
          int s = sa[j];
          int slot = atomicAdd(&cursor[d], 1);
          csr8[slot] = make_int2(s, __float_as_int(dinv[s] * dinv[d]));
        }
      }
    }
  }
}

// ---------------- weight prep: W[K][M] fp32 -> Bt[col][k] bf16 hi/lo ----------------

__global__ void k_prep_w(const float* __restrict__ W1, const float* __restrict__ W2,
                         const float* __restrict__ Wd1, const float* __restrict__ Wd2,
                         unsigned short* __restrict__ w1hi, unsigned short* __restrict__ w1lo,
                         unsigned short* __restrict__ w2hi, unsigned short* __restrict__ w2lo,
                         unsigned short* __restrict__ wd1hi, unsigned short* __restrict__ wd1lo,
                         unsigned short* __restrict__ wd2hi, unsigned short* __restrict__ wd2lo) {
  const float* src; unsigned short *hi, *lo; int K, M;
  switch (blockIdx.x) {
    case 0:  src = W1;  hi = w1hi;  lo = w1lo;  K = 128; M = 64;  break;
    case 1:  src = W2;  hi = w2hi;  lo = w2lo;  K = 64;  M = 32;  break;
    case 2:  src = Wd1; hi = wd1hi; lo = wd1lo; K = 32;  M = 64;  break;
    default: src = Wd2; hi = wd2hi; lo = wd2lo; K = 64;  M = 128; break;
  }
  int KP = K + 8;
  for (int i = threadIdx.x; i < K * M; i += 256) {
    int k = i / M, c = i % M;
    float v = src[i];
    unsigned short h = f2bf(v);
    hi[c * KP + k] = h;
    lo[c * KP + k] = f2bf(v - bf2f(h));
  }
}

// ---------------- MFMA GEMM: Y[N,M] = X[N,K] @ W[K,M], fp32 in, bf16 out ----------------
// Output stored as bf16 (the aggregate gathers it; halves gather traffic).

template<int NODES, int K, int M>
__global__ __launch_bounds__(256) void k_mfma_gemm(const float* __restrict__ X,
                                                   const unsigned short* __restrict__ Bhi,
                                                   const unsigned short* __restrict__ Blo,
                                                   unsigned short* __restrict__ Y16) {
  constexpr int KP     = K + 8;
  constexpr int NSTRIP = M / 16;
  constexpr int KSTEPS = K / 32;
  constexpr int MTW    = (NODES / 16) * NSTRIP / 4;
  __shared__ __align__(16) unsigned short Ahi[NODES * KP];
  __shared__ __align__(16) unsigned short Alo[NODES * KP];

  int t = threadIdx.x;
  int node0 = blockIdx.x * NODES;

  for (int i = t; i < NODES * K / 4; i += 256) {
    int n = i / (K / 4), f4 = i % (K / 4);
    float4 v = make_float4(0.f, 0.f, 0.f, 0.f);
    if (node0 + n < N_NODES) v = ((const float4*)(X + (size_t)(node0 + n) * K))[f4];
    int base = n * KP + f4 * 4;
    float vv[4] = {v.x, v.y, v.z, v.w};
#pragma unroll
    for (int j = 0; j < 4; j++) {
      unsigned short h = f2bf(vv[j]);
      Ahi[base + j] = h;
      Alo[base + j] = f2bf(vv[j] - bf2f(h));
    }
  }
  __syncthreads();

  int w = t >> 6, lane = t & 63;
  int quad = lane >> 4, r16 = lane & 15;
  int strip = w % NSTRIP;

  bf16x8 bh[KSTEPS], bl[KSTEPS];
  const unsigned short* bp = Bhi + (strip * 16 + r16) * KP + quad * 8;
  const unsigned short* bq = Blo + (strip * 16 + r16) * KP + quad * 8;
#pragma unroll
  for (int ks = 0; ks < KSTEPS; ks++) {
    bh[ks] = *(const bf16x8*)(bp + ks * 32);
    bl[ks] = *(const bf16x8*)(bq + ks * 32);
  }

#pragma unroll
  for (int c = 0; c < MTW; c++) {
    int mt = (w / NSTRIP) * MTW + c;
    f32x4 acc = {0.f, 0.f, 0.f, 0.f};
    const unsigned short* ap = &Ahi[(mt * 16 + r16) * KP + quad * 8];
    const unsigned short* aq = &Alo[(mt * 16 + r16) * KP + quad * 8];
#pragma unroll
    for (int ks = 0; ks < KSTEPS; ks++) {
      bf16x8 ah = *(const bf16x8*)(ap + ks * 32);
      bf16x8 al = *(const bf16x8*)(aq + ks * 32);
      acc = __builtin_amdgcn_mfma_f32_16x16x32_bf16(ah, bh[ks], acc, 0, 0, 0);
      acc = __builtin_amdgcn_mfma_f32_16x16x32_bf16(ah, bl[ks], acc, 0, 0, 0);
      acc = __builtin_amdgcn_mfma_f32_16x16x32_bf16(al, bh[ks], acc, 0, 0, 0);
    }
    int gn  = node0 + mt * 16 + quad * 4;
    int col = strip * 16 + r16;
#pragma unroll
    for (int r = 0; r < 4; r++) {
      if (gn + r < N_NODES) Y16[(size_t)(gn + r) * M + col] = f2bf(acc[r]);
    }
  }
}

// ---------------- aggregation (gather side, wave per node, bf16 table) ----------------
// Round 6 restructure: multi-edge gathers. The wave is split into GROUPS
// lane-groups; each lane loads ushort4 (4 features), so ONE wave VMEM
// instruction gathers GROUPS different source rows (4 for FEAT=64, 8 for
// FEAT=32). Two batches in flight per iteration -> 8/16 edges per dependent
// round-trip, vs 4/2 in the previous wave-per-edge-row scheme. Cross-group
// partials fold with shfl_xor; final store is a contiguous float4 by group 0.

template<int FEAT, bool RELU>
__global__ __launch_bounds__(256) void k_aggregate(const unsigned short* __restrict__ H16,
                            const int* __restrict__ offsets,
                            const int2* __restrict__ csr8,
                            const float* __restrict__ dinv, const float* __restrict__ bias,
                            float* __restrict__ OUT) {
  constexpr int LPG    = FEAT / 4;   // lanes per edge-group (16 or 8)
  constexpr int GROUPS = 64 / LPG;   // edges gathered per wave instr (4 or 8)

  int node = blockIdx.x * 4 + (threadIdx.x >> 6);
  int lane = threadIdx.x & 63;
  if (node >= N_NODES) return;
  int beg = offsets[node], end = offsets[node + 1];
  int g  = lane / LPG;               // which edge of the batch
  int f4 = lane % LPG;               // which feature quad

  float a0 = 0.f, a1 = 0.f, a2 = 0.f, a3 = 0.f;

  int p = beg;
  // main loop: 2*GROUPS edges per iteration, both batches' gathers in flight
  for (; p + 2 * GROUPS <= end; p += 2 * GROUPS) {
    int2 e0 = csr8[p + g];
    int2 e1 = csr8[p + GROUPS + g];
    ushort4 h0 = *(const ushort4*)(H16 + (size_t)e0.x * FEAT + f4 * 4);
    ushort4 h1 = *(const ushort4*)(H16 + (size_t)e1.x * FEAT + f4 * 4);
    float w0 = __int_as_float(e0.y), w1 = __int_as_float(e1.y);
    a0 += bf2f(h0.x) * w0; a1 += bf2f(h0.y) * w0;
    a2 += bf2f(h0.z) * w0; a3 += bf2f(h0.w) * w0;
    a0 += bf2f(h1.x) * w1; a1 += bf2f(h1.y) * w1;
    a2 += bf2f(h1.z) * w1; a3 += bf2f(h1.w) * w1;
  }
  // remainder: masked batches of GROUPS edges (inactive lanes read own row w/ w=0)
  for (; p < end; p += GROUPS) {
    int q = p + g;
    int2 e = (q < end) ? csr8[q] : make_int2(node, 0);
    ushort4 h = *(const ushort4*)(H16 + (size_t)e.x * FEAT + f4 * 4);
    float w = __int_as_float(e.y);
    a0 += bf2f(h.x) * w; a1 += bf2f(h.y) * w;
    a2 += bf2f(h.z) * w; a3 += bf2f(h.w) * w;
  }

  // fold edge-groups together (g lives in the upper lane bits)
#pragma unroll
  for (int off = LPG; off < 64; off <<= 1) {
    a0 += __shfl_xor(a0, off, 64);
    a1 += __shfl_xor(a1, off, 64);
    a2 += __shfl_xor(a2, off, 64);
    a3 += __shfl_xor(a3, off, 64);
  }

  if (g == 0) {
    float di = dinv[node];
    float sw = di * di;                         // self-loop weight
    ushort4 hs = *(const ushort4*)(H16 + (size_t)node * FEAT + f4 * 4);
    float4 bv = *(const float4*)(bias + f4 * 4);
    a0 += bf2f(hs.x) * sw + bv.x;
    a1 += bf2f(hs.y) * sw + bv.y;
    a2 += bf2f(hs.z) * sw + bv.z;
    a3 += bf2f(hs.w) * sw + bv.w;
    if (RELU) {
      a0 = fmaxf(a0, 0.f); a1 = fmaxf(a1, 0.f);
      a2 = fmaxf(a2, 0.f); a3 = fmaxf(a3, 0.f);
    }
    float4 o; o.x = a0; o.y = a1; o.z = a2; o.w = a3;
    *(float4*)(OUT + (size_t)node * FEAT + f4 * 4) = o;
  }
}

// ---------------- decoder: fused 2-stage MFMA ----------------

__global__ __launch_bounds__(256) void k_decoder_mfma(
    const float* __restrict__ Z,
    const unsigned short* __restrict__ B1hi, const unsigned short* __restrict__ B1lo,
    const float* __restrict__ bd1,
    const unsigned short* __restrict__ B2hi, const unsigned short* __restrict__ B2lo,
    const float* __restrict__ bd2, float* __restrict__ RECON) {
  constexpr int KP1 = 40;   // 32+8
  constexpr int KP2 = 72;   // 64+8
  __shared__ __align__(16) unsigned short Azhi[64 * KP1];
  __shared__ __align__(16) unsigned short Azlo[64 * KP1];
  __shared__ __align__(16) unsigned short H3hi[64 * KP2];
  __shared__ __align__(16) unsigned short H3lo[64 * KP2];
  int t = threadIdx.x;
  int node0 = blockIdx.x * 64;

  for (int i = t; i < 512; i += 256) {
    int n = i >> 3, f4 = i & 7;
    float4 v = make_float4(0.f, 0.f, 0.f, 0.f);
    if (node0 + n < N_NODES) v = ((const float4*)(Z + (size_t)(node0 + n) * 32))[f4];
    int base = n * KP1 + f4 * 4;
    float vv[4] = {v.x, v.y, v.z, v.w};
#pragma unroll
    for (int j = 0; j < 4; j++) {
      unsigned short h = f2bf(vv[j]);
      Azhi[base + j] = h;
      Azlo[base + j] = f2bf(vv[j] - bf2f(h));
    }
  }
  __syncthreads();

  int w = t >> 6, lane = t & 63;
  int quad = lane >> 4, r16 = lane & 15;

  {
    int col = w * 16 + r16;
    float bias1 = bd1[col];
    bf16x8 bh = *(const bf16x8*)(B1hi + col * KP1 + quad * 8);
    bf16x8 bl = *(const bf16x8*)(B1lo + col * KP1 + quad * 8);
#pragma unroll
    for (int m = 0; m < 4; m++) {
      bf16x8 ah = *(const bf16x8*)(Azhi + (m * 16 + r16) * KP1 + quad * 8);
      bf16x8 al = *(const bf16x8*)(Azlo + (m * 16 + r16) * KP1 + quad * 8);
      f32x4 acc = {0.f, 0.f, 0.f, 0.f};
      acc = __builtin_amdgcn_mfma_f32_16x16x32_bf16(ah, bh, acc, 0, 0, 0);
      acc = __builtin_amdgcn_mfma_f32_16x16x32_bf16(ah, bl, acc, 0, 0, 0);
      acc = __builtin_amdgcn_mfma_f32_16x16x32_bf16(al, bh, acc, 0, 0, 0);
#pragma unroll
      for (int r = 0; r < 4; r++) {
        int row = m * 16 + quad * 4 + r;
        float hv = fmaxf(acc[r] + bias1, 0.f);
        unsigned short h = f2bf(hv);
        H3hi[row * KP2 + col] = h;
        H3lo[row * KP2 + col] = f2bf(hv - bf2f(h));
      }
    }
  }
  __syncthreads();

#pragma unroll
  for (int sp = 0; sp < 2; sp++) {
    int strip = w + sp * 4;
    int col = strip * 16 + r16;
    float bias2 = bd2[col];
    const unsigned short* b2h = B2hi + col * KP2 + quad * 8;
    const unsigned short* b2l = B2lo + col * KP2 + quad * 8;
    bf16x8 bh0 = *(const bf16x8*)(b2h);
    bf16x8 bh1 = *(const bf16x8*)(b2h + 32);
    bf16x8 bl0 = *(const bf16x8*)(b2l);
    bf16x8 bl1 = *(const bf16x8*)(b2l + 32);
#pragma unroll
    for (int m = 0; m < 4; m++) {
      const unsigned short* ahp = H3hi + (m * 16 + r16) * KP2 + quad * 8;
      const unsigned short* alp = H3lo + (m * 16 + r16) * KP2 + quad * 8;
      bf16x8 ah0 = *(const bf16x8*)(ahp);
      bf16x8 ah1 = *(const bf16x8*)(ahp + 32);
      bf16x8 al0 = *(const bf16x8*)(alp);
      bf16x8 al1 = *(const bf16x8*)(alp + 32);
      f32x4 acc = {0.f, 0.f, 0.f, 0.f};
      acc = __builtin_amdgcn_mfma_f32_16x16x32_bf16(ah0, bh0, acc, 0, 0, 0);
      acc = __builtin_amdgcn_mfma_f32_16x16x32_bf16(ah1, bh1, acc, 0, 0, 0);
      acc = __builtin_amdgcn_mfma_f32_16x16x32_bf16(ah0, bl0, acc, 0, 0, 0);
      acc = __builtin_amdgcn_mfma_f32_16x16x32_bf16(ah1, bl1, acc, 0, 0, 0);
      acc = __builtin_amdgcn_mfma_f32_16x16x32_bf16(al0, bh0, acc, 0, 0, 0);
      acc = __builtin_amdgcn_mfma_f32_16x16x32_bf16(al1, bh1, acc, 0, 0, 0);
#pragma unroll
      for (int r = 0; r < 4; r++) {
        int n = node0 + m * 16 + quad * 4 + r;
        if (n < N_NODES) RECON[(size_t)n * 128 + col] = acc[r] + bias2;
      }
    }
  }
}

// ---------------- launch ----------------

extern "C" void kernel_launch(void* const* d_in, const int* in_sizes, int n_in,
                              void* d_out, int out_size, void* d_ws, size_t ws_size,
                              hipStream_t stream) {
  const float* x    = (const float*)d_in[0];
  const int*   eidx = (const int*)d_in[1];     // int32 per harness contract
  const int*   esrc = eidx;                    // edge_index[0]
  const int*   edst = eidx + N_EDGES;          // edge_index[1]
  const float* W1  = (const float*)d_in[2];
  const float* b1  = (const float*)d_in[3];
  const float* W2  = (const float*)d_in[4];
  const float* b2  = (const float*)d_in[5];
  const float* Wd1 = (const float*)d_in[6];
  const float* bd1 = (const float*)d_in[7];
  const float* Wd2 = (const float*)d_in[8];
  const float* bd2 = (const float*)d_in[9];

  float* recon = (float*)d_out;                                  // [N,128]
  float* z     = (float*)d_out + (size_t)N_NODES * D_INF;        // [N,32]
  // Scratch in the dead recon region (51.2 MB, written only by k_decoder_mfma):
  //   h1_16 [N,64] bf16 @ +0         (12.8 MB)
  //   z1    [N,64] fp32 @ +12.8 MB   (25.6 MB)
  //   h2_16 [N,32] bf16 @ +38.4 MB   ( 6.4 MB)   -> total 44.8 MB < 51.2 MB
  unsigned short* h1_16 = (unsigned short*)recon;
  float*          z1    = (float*)((char*)recon + 12800000);
  unsigned short* h2_16 = (unsigned short*)((char*)recon + 38400000);

  char* ws = (char*)d_ws;
  int*   counts  = (int*)(ws + 0);
  int*   offsets = (int*)(ws + 409600);
  int*   cursor  = (int*)(ws + 819200);
  float* dinv    = (float*)(ws + 1228800);
  int*   bsums   = (int*)(ws + 1638400);
  int*   bbase   = (int*)(ws + 1639424);
  int2*  csr8    = (int2*)(ws + 1640448);      // 12,800,000 B packed (src,w)
  unsigned short* w1hi  = (unsigned short*)(ws + 14440448);
  unsigned short* w1lo  = (unsigned short*)(ws + 14457856);
  unsigned short* w2hi  = (unsigned short*)(ws + 14475264);
  unsigned short* w2lo  = (unsigned short*)(ws + 14479872);
  unsigned short* wd1hi = (unsigned short*)(ws + 14484480);
  unsigned short* wd1lo = (unsigned short*)(ws + 14489600);
  unsigned short* wd2hi = (unsigned short*)(ws + 14494720);
  unsigned short* wd2lo = (unsigned short*)(ws + 14513152);
  // total ws use: 14,531,584 B

  k_zero<<<(N_NODES + 255) / 256, 256, 0, stream>>>(counts);
  k_count<<<(N_EDGES + 255) / 256, 256, 0, stream>>>(edst, counts);
  k_blocksum<<<NB, 256, 0, stream>>>(counts, bsums);
  k_scanblocks<<<1, 128, 0, stream>>>(bsums, bbase, offsets);
  k_scanchunk<<<NB, 256, 0, stream>>>(counts, bbase, offsets, cursor, dinv);
  k_build<<<BUILD_CHUNKS * BUILD_PARTS, 256, 0, stream>>>(esrc, edst, dinv, cursor, csr8);
  k_prep_w<<<4, 256, 0, stream>>>(W1, W2, Wd1, Wd2, w1hi, w1lo, w2hi, w2lo,
                                  wd1hi, wd1lo, wd2hi, wd2lo);

  // h1 = x @ W1  (bf16 out)
  k_mfma_gemm<64, 128, 64><<<(N_NODES + 63) / 64, 256, 0, stream>>>(x, w1hi, w1lo, h1_16);
  // z1 = relu(agg(h1) + b1)  (fp32 out)
  k_aggregate<64, true><<<(N_NODES + 3) / 4, 256, 0, stream>>>(h1_16, offsets, csr8, dinv, b1, z1);
  // h2 = z1 @ W2  (bf16 out)
  k_mfma_gemm<64, 64, 32><<<(N_NODES + 63) / 64, 256, 0, stream>>>(z1, w2hi, w2lo, h2_16);
  // z = agg(h2) + b2  (latent output, fp32)
  k_aggregate<32, false><<<(N_NODES + 3) / 4, 256, 0, stream>>>(h2_16, offsets, csr8, dinv, b2, z);
  // recon = relu(z@Wd1+bd1) @ Wd2 + bd2
  k_decoder_mfma<<<(N_NODES + 63) / 64, 256, 0, stream>>>(z, wd1hi, wd1lo, bd1,
                                                          wd2hi, wd2lo, bd2, recon);
}

// Round 2
// 391.721 us; speedup vs baseline: 1.2133x; 1.0372x over previous
//
#include <hip/hip_runtime.h>
#include <stdint.h>

#define N_NODES 100000
#define N_EDGES 1600000
#define D_INF   128
#define D_HID   64
#define D_LAT   32
#define NB      98      // ceil(N_NODES/1024)

typedef __attribute__((ext_vector_type(8))) short bf16x8;
typedef __attribute__((ext_vector_type(4))) float f32x4;

__device__ __forceinline__ unsigned short f2bf(float v) {
  union { float f; unsigned int u; } x; x.f = v;
  unsigned int u = x.u + 0x7FFF + ((x.u >> 16) & 1);   // RNE
  return (unsigned short)(u >> 16);
}
__device__ __forceinline__ float bf2f(unsigned short h) {
  union { unsigned int u; float f; } x; x.u = ((unsigned int)h) << 16;
  return x.f;
}

// ---------------- CSR build ----------------

__global__ void k_zero(int* __restrict__ counts) {
  int i = blockIdx.x * 256 + threadIdx.x;
  if (i < N_NODES) counts[i] = 0;
}

__global__ void k_count(const int* __restrict__ dst, int* __restrict__ counts) {
  int e = blockIdx.x * 256 + threadIdx.x;
  if (e < N_EDGES) atomicAdd(&counts[dst[e]], 1);
}

__global__ void k_blocksum(const int* __restrict__ counts, int* __restrict__ bsums) {
  __shared__ int red[4];
  int base = blockIdx.x * 1024 + threadIdx.x * 4;
  int s = 0;
#pragma unroll
  for (int j = 0; j < 4; j++) { int i = base + j; if (i < N_NODES) s += counts[i]; }
#pragma unroll
  for (int off = 32; off > 0; off >>= 1) s += __shfl_down(s, off, 64);
  if ((threadIdx.x & 63) == 0) red[threadIdx.x >> 6] = s;
  __syncthreads();
  if (threadIdx.x == 0) bsums[blockIdx.x] = red[0] + red[1] + red[2] + red[3];
}

__global__ void k_scanblocks(const int* __restrict__ bsums, int* __restrict__ bbase,
                             int* __restrict__ offsets) {
  __shared__ int sh[128];
  int t = threadIdx.x;
  int v = (t < NB) ? bsums[t] : 0;
  sh[t] = v;
  __syncthreads();
  int incl = v;
#pragma unroll
  for (int off = 1; off < 128; off <<= 1) {
    int x = (t >= off) ? sh[t - off] : 0;
    __syncthreads();
    incl += x;
    sh[t] = incl;
    __syncthreads();
  }
  if (t < NB) bbase[t] = incl - v;
  if (t == NB - 1) offsets[N_NODES] = incl;   // == N_EDGES
}

__global__ void k_scanchunk(const int* __restrict__ counts, const int* __restrict__ bbase,
                            int* __restrict__ offsets, int* __restrict__ cursor,
                            float* __restrict__ dinv) {
  __shared__ int sh[256];
  int b = blockIdx.x, t = threadIdx.x;
  int base = b * 1024 + t * 4;
  int v[4]; int s = 0;
#pragma unroll
  for (int j = 0; j < 4; j++) { v[j] = (base + j < N_NODES) ? counts[base + j] : 0; s += v[j]; }
  sh[t] = s;
  __syncthreads();
  int incl = s;
#pragma unroll
  for (int off = 1; off < 256; off <<= 1) {
    int x = (t >= off) ? sh[t - off] : 0;
    __syncthreads();
    incl += x;
    sh[t] = incl;
    __syncthreads();
  }
  int run = bbase[b] + incl - s;
#pragma unroll
  for (int j = 0; j < 4; j++) {
    int i = base + j;
    if (i < N_NODES) {
      offsets[i] = run;
      cursor[i]  = run;
      dinv[i]    = rsqrtf((float)(v[j] + 1));   // deg = in-count + self-loop
      run += v[j];
    }
  }
}

// Two-pass binned CSR build (round 7).
// Pass A: bin (src,dst) pairs by dst>>9 into a staging buffer, coalesced on
// both sides (LDS counting sort per block + per-bucket contiguous runs).
// Pass B: per bucket, scatter within a ~65 KB L2-resident region to exact
// per-node slots. Replaces the 8x-re-read + 8x-write-amplified k_build.

#define NBKT      196    // ceil(100000 / 512)
#define BKT_SHIFT 9      // 512 nodes per bucket
#define EPB       4096   // edges per pass-A block
#define ABLOCKS   391    // ceil(1600000 / 4096)
#define SPLITB    4      // pass-B blocks per bucket

__global__ void k_initbcur(const int* __restrict__ offsets, int* __restrict__ bcur) {
  int t = threadIdx.x;
  if (t < NBKT) bcur[t] = offsets[t << BKT_SHIFT];
}

__global__ __launch_bounds__(256) void k_binA(const int* __restrict__ esrc,
                                              const int* __restrict__ edst,
                                              int* __restrict__ bcur,
                                              int2* __restrict__ stage) {
  __shared__ int cnt[NBKT];
  __shared__ int sc[256];
  __shared__ int garel[NBKT];
  __shared__ int pos[NBKT];
  __shared__ __align__(16) int2 stg[EPB];   // 32 KB
  __shared__ int gaddr[EPB];                // 16 KB
  int t = threadIdx.x;
  int e0 = blockIdx.x * EPB;

  for (int i = t; i < NBKT; i += 256) cnt[i] = 0;
  __syncthreads();

  // load 16 edges/thread into registers (coalesced int4)
  int ds[16], ss[16];
  const int4* s4 = (const int4*)esrc;
  const int4* d4 = (const int4*)edst;
#pragma unroll
  for (int i = 0; i < 4; i++) {
    int idx4 = (e0 >> 2) + i * 256 + t;
    int4 dd = make_int4(-1, -1, -1, -1);
    int4 sv = make_int4(0, 0, 0, 0);
    if (idx4 < N_EDGES / 4) { dd = d4[idx4]; sv = s4[idx4]; }
    ds[i*4+0] = dd.x; ds[i*4+1] = dd.y; ds[i*4+2] = dd.z; ds[i*4+3] = dd.w;
    ss[i*4+0] = sv.x; ss[i*4+1] = sv.y; ss[i*4+2] = sv.z; ss[i*4+3] = sv.w;
  }
#pragma unroll
  for (int j = 0; j < 16; j++)
    if (ds[j] >= 0) atomicAdd(&cnt[ds[j] >> BKT_SHIFT], 1);
  __syncthreads();

  // block-level exclusive prefix over bucket counts
  int c = (t < NBKT) ? cnt[t] : 0;
  sc[t] = c;
  __syncthreads();
  int incl = c;
#pragma unroll
  for (int off = 1; off < 256; off <<= 1) {
    int x = (t >= off) ? sc[t - off] : 0;
    __syncthreads();
    incl += x;
    sc[t] = incl;
    __syncthreads();
  }
  if (t < NBKT) {
    int lb = incl - c;                                   // local base
    int gb = (c > 0) ? atomicAdd(&bcur[t], c) : 0;       // reserve global run
    garel[t] = gb - lb;
    pos[t]   = lb;
  }
  __syncthreads();

  // place into LDS staging in bucket order; remember global address
#pragma unroll
  for (int j = 0; j < 16; j++) {
    if (ds[j] >= 0) {
      int b  = ds[j] >> BKT_SHIFT;
      int lp = atomicAdd(&pos[b], 1);
      stg[lp]   = make_int2(ss[j], ds[j]);
      gaddr[lp] = garel[b] + lp;
    }
  }
  __syncthreads();

  // copy out: consecutive lanes -> mostly-consecutive global addresses
  int nval = N_EDGES - e0; if (nval > EPB) nval = EPB;
  for (int i = t; i < nval; i += 256)
    stage[gaddr[i]] = stg[i];
}

__global__ __launch_bounds__(256) void k_binB(const int2* __restrict__ stage,
                                              const int* __restrict__ offsets,
                                              int* __restrict__ cursor,
                                              const float* __restrict__ dinv,
                                              int2* __restrict__ csr8) {
  int b   = blockIdx.x / SPLITB;
  int sub = blockIdx.x % SPLITB;
  int nlo = b << BKT_SHIFT;
  int nhi = nlo + (1 << BKT_SHIFT); if (nhi > N_NODES) nhi = N_NODES;
  int rbeg = offsets[nlo], rend = offsets[nhi];
  for (int i = rbeg + sub * 256 + threadIdx.x; i < rend; i += SPLITB * 256) {
    int2 e = stage[i];
    int slot = atomicAdd(&cursor[e.y], 1);
    float w = dinv[e.x] * dinv[e.y];
    csr8[slot] = make_int2(e.x, __float_as_int(w));
  }
}

// ---------------- weight prep: W[K][M] fp32 -> Bt[col][k] bf16 hi/lo ----------------

__global__ void k_prep_w(const float* __restrict__ W1, const float* __restrict__ W2,
                         const float* __restrict__ Wd1, const float* __restrict__ Wd2,
                         unsigned short* __restrict__ w1hi, unsigned short* __restrict__ w1lo,
                         unsigned short* __restrict__ w2hi, unsigned short* __restrict__ w2lo,
                         unsigned short* __restrict__ wd1hi, unsigned short* __restrict__ wd1lo,
                         unsigned short* __restrict__ wd2hi, unsigned short* __restrict__ wd2lo) {
  const float* src; unsigned short *hi, *lo; int K, M;
  switch (blockIdx.x) {
    case 0:  src = W1;  hi = w1hi;  lo = w1lo;  K = 128; M = 64;  break;
    case 1:  src = W2;  hi = w2hi;  lo = w2lo;  K = 64;  M = 32;  break;
    case 2:  src = Wd1; hi = wd1hi; lo = wd1lo; K = 32;  M = 64;  break;
    default: src = Wd2; hi = wd2hi; lo = wd2lo; K = 64;  M = 128; break;
  }
  int KP = K + 8;
  for (int i = threadIdx.x; i < K * M; i += 256) {
    int k = i / M, c = i % M;
    float v = src[i];
    unsigned short h = f2bf(v);
    hi[c * KP + k] = h;
    lo[c * KP + k] = f2bf(v - bf2f(h));
  }
}

// ---------------- MFMA GEMM: Y[N,M] = X[N,K] @ W[K,M], fp32 in, bf16 out ----------------
// Output stored as bf16 (the aggregate gathers it; halves gather traffic).

template<int NODES, int K, int M>
__global__ __launch_bounds__(256) void k_mfma_gemm(const float* __restrict__ X,
                                                   const unsigned short* __restrict__ Bhi,
                                                   const unsigned short* __restrict__ Blo,
                                                   unsigned short* __restrict__ Y16) {
  constexpr int KP     = K + 8;
  constexpr int NSTRIP = M / 16;
  constexpr int KSTEPS = K / 32;
  constexpr int MTW    = (NODES / 16) * NSTRIP / 4;
  __shared__ __align__(16) unsigned short Ahi[NODES * KP];
  __shared__ __align__(16) unsigned short Alo[NODES * KP];

  int t = threadIdx.x;
  int node0 = blockIdx.x * NODES;

  for (int i = t; i < NODES * K / 4; i += 256) {
    int n = i / (K / 4), f4 = i % (K / 4);
    float4 v = make_float4(0.f, 0.f, 0.f, 0.f);
    if (node0 + n < N_NODES) v = ((const float4*)(X + (size_t)(node0 + n) * K))[f4];
    int base = n * KP + f4 * 4;
    float vv[4] = {v.x, v.y, v.z, v.w};
#pragma unroll
    for (int j = 0; j < 4; j++) {
      unsigned short h = f2bf(vv[j]);
      Ahi[base + j] = h;
      Alo[base + j] = f2bf(vv[j] - bf2f(h));
    }
  }
  __syncthreads();

  int w = t >> 6, lane = t & 63;
  int quad = lane >> 4, r16 = lane & 15;
  int strip = w % NSTRIP;

  bf16x8 bh[KSTEPS], bl[KSTEPS];
  const unsigned short* bp = Bhi + (strip * 16 + r16) * KP + quad * 8;
  const unsigned short* bq = Blo + (strip * 16 + r16) * KP + quad * 8;
#pragma unroll
  for (int ks = 0; ks < KSTEPS; ks++) {
    bh[ks] = *(const bf16x8*)(bp + ks * 32);
    bl[ks] = *(const bf16x8*)(bq + ks * 32);
  }

#pragma unroll
  for (int c = 0; c < MTW; c++) {
    int mt = (w / NSTRIP) * MTW + c;
    f32x4 acc = {0.f, 0.f, 0.f, 0.f};
    const unsigned short* ap = &Ahi[(mt * 16 + r16) * KP + quad * 8];
    const unsigned short* aq = &Alo[(mt * 16 + r16) * KP + quad * 8];
#pragma unroll
    for (int ks = 0; ks < KSTEPS; ks++) {
      bf16x8 ah = *(const bf16x8*)(ap + ks * 32);
      bf16x8 al = *(const bf16x8*)(aq + ks * 32);
      acc = __builtin_amdgcn_mfma_f32_16x16x32_bf16(ah, bh[ks], acc, 0, 0, 0);
      acc = __builtin_amdgcn_mfma_f32_16x16x32_bf16(ah, bl[ks], acc, 0, 0, 0);
      acc = __builtin_amdgcn_mfma_f32_16x16x32_bf16(al, bh[ks], acc, 0, 0, 0);
    }
    int gn  = node0 + mt * 16 + quad * 4;
    int col = strip * 16 + r16;
#pragma unroll
    for (int r = 0; r < 4; r++) {
      if (gn + r < N_NODES) Y16[(size_t)(gn + r) * M + col] = f2bf(acc[r]);
    }
  }
}

// ---------------- aggregation (gather side, multi-edge wave gathers) ----------------

template<int FEAT, bool RELU>
__global__ __launch_bounds__(256) void k_aggregate(const unsigned short* __restrict__ H16,
                            const int* __restrict__ offsets,
                            const int2* __restrict__ csr8,
                            const float* __restrict__ dinv, const float* __restrict__ bias,
                            float* __restrict__ OUT) {
  constexpr int LPG    = FEAT / 4;   // lanes per edge-group (16 or 8)
  constexpr int GROUPS = 64 / LPG;   // edges gathered per wave instr (4 or 8)

  int node = blockIdx.x * 4 + (threadIdx.x >> 6);
  int lane = threadIdx.x & 63;
  if (node >= N_NODES) return;
  int beg = offsets[node], end = offsets[node + 1];
  int g  = lane / LPG;               // which edge of the batch
  int f4 = lane % LPG;               // which feature quad

  float a0 = 0.f, a1 = 0.f, a2 = 0.f, a3 = 0.f;

  int p = beg;
  // main loop: 2*GROUPS edges per iteration, both batches' gathers in flight
  for (; p + 2 * GROUPS <= end; p += 2 * GROUPS) {
    int2 e0 = csr8[p + g];
    int2 e1 = csr8[p + GROUPS + g];
    ushort4 h0 = *(const ushort4*)(H16 + (size_t)e0.x * FEAT + f4 * 4);
    ushort4 h1 = *(const ushort4*)(H16 + (size_t)e1.x * FEAT + f4 * 4);
    float w0 = __int_as_float(e0.y), w1 = __int_as_float(e1.y);
    a0 += bf2f(h0.x) * w0; a1 += bf2f(h0.y) * w0;
    a2 += bf2f(h0.z) * w0; a3 += bf2f(h0.w) * w0;
    a0 += bf2f(h1.x) * w1; a1 += bf2f(h1.y) * w1;
    a2 += bf2f(h1.z) * w1; a3 += bf2f(h1.w) * w1;
  }
  // remainder: masked batches of GROUPS edges (inactive lanes read own row w/ w=0)
  for (; p < end; p += GROUPS) {
    int q = p + g;
    int2 e = (q < end) ? csr8[q] : make_int2(node, 0);
    ushort4 h = *(const ushort4*)(H16 + (size_t)e.x * FEAT + f4 * 4);
    float w = __int_as_float(e.y);
    a0 += bf2f(h.x) * w; a1 += bf2f(h.y) * w;
    a2 += bf2f(h.z) * w; a3 += bf2f(h.w) * w;
  }

  // fold edge-groups together (g lives in the upper lane bits)
#pragma unroll
  for (int off = LPG; off < 64; off <<= 1) {
    a0 += __shfl_xor(a0, off, 64);
    a1 += __shfl_xor(a1, off, 64);
    a2 += __shfl_xor(a2, off, 64);
    a3 += __shfl_xor(a3, off, 64);
  }

  if (g == 0) {
    float di = dinv[node];
    float sw = di * di;                         // self-loop weight
    ushort4 hs = *(const ushort4*)(H16 + (size_t)node * FEAT + f4 * 4);
    float4 bv = *(const float4*)(bias + f4 * 4);
    a0 += bf2f(hs.x) * sw + bv.x;
    a1 += bf2f(hs.y) * sw + bv.y;
    a2 += bf2f(hs.z) * sw + bv.z;
    a3 += bf2f(hs.w) * sw + bv.w;
    if (RELU) {
      a0 = fmaxf(a0, 0.f); a1 = fmaxf(a1, 0.f);
      a2 = fmaxf(a2, 0.f); a3 = fmaxf(a3, 0.f);
    }
    float4 o; o.x = a0; o.y = a1; o.z = a2; o.w = a3;
    *(float4*)(OUT + (size_t)node * FEAT + f4 * 4) = o;
  }
}

// ---------------- decoder: fused 2-stage MFMA ----------------

__global__ __launch_bounds__(256) void k_decoder_mfma(
    const float* __restrict__ Z,
    const unsigned short* __restrict__ B1hi, const unsigned short* __restrict__ B1lo,
    const float* __restrict__ bd1,
    const unsigned short* __restrict__ B2hi, const unsigned short* __restrict__ B2lo,
    const float* __restrict__ bd2, float* __restrict__ RECON) {
  constexpr int KP1 = 40;   // 32+8
  constexpr int KP2 = 72;   // 64+8
  __shared__ __align__(16) unsigned short Azhi[64 * KP1];
  __shared__ __align__(16) unsigned short Azlo[64 * KP1];
  __shared__ __align__(16) unsigned short H3hi[64 * KP2];
  __shared__ __align__(16) unsigned short H3lo[64 * KP2];
  int t = threadIdx.x;
  int node0 = blockIdx.x * 64;

  for (int i = t; i < 512; i += 256) {
    int n = i >> 3, f4 = i & 7;
    float4 v = make_float4(0.f, 0.f, 0.f, 0.f);
    if (node0 + n < N_NODES) v = ((const float4*)(Z + (size_t)(node0 + n) * 32))[f4];
    int base = n * KP1 + f4 * 4;
    float vv[4] = {v.x, v.y, v.z, v.w};
#pragma unroll
    for (int j = 0; j < 4; j++) {
      unsigned short h = f2bf(vv[j]);
      Azhi[base + j] = h;
      Azlo[base + j] = f2bf(vv[j] - bf2f(h));
    }
  }
  __syncthreads();

  int w = t >> 6, lane = t & 63;
  int quad = lane >> 4, r16 = lane & 15;

  {
    int col = w * 16 + r16;
    float bias1 = bd1[col];
    bf16x8 bh = *(const bf16x8*)(B1hi + col * KP1 + quad * 8);
    bf16x8 bl = *(const bf16x8*)(B1lo + col * KP1 + quad * 8);
#pragma unroll
    for (int m = 0; m < 4; m++) {
      bf16x8 ah = *(const bf16x8*)(Azhi + (m * 16 + r16) * KP1 + quad * 8);
      bf16x8 al = *(const bf16x8*)(Azlo + (m * 16 + r16) * KP1 + quad * 8);
      f32x4 acc = {0.f, 0.f, 0.f, 0.f};
      acc = __builtin_amdgcn_mfma_f32_16x16x32_bf16(ah, bh, acc, 0, 0, 0);
      acc = __builtin_amdgcn_mfma_f32_16x16x32_bf16(ah, bl, acc, 0, 0, 0);
      acc = __builtin_amdgcn_mfma_f32_16x16x32_bf16(al, bh, acc, 0, 0, 0);
#pragma unroll
      for (int r = 0; r < 4; r++) {
        int row = m * 16 + quad * 4 + r;
        float hv = fmaxf(acc[r] + bias1, 0.f);
        unsigned short h = f2bf(hv);
        H3hi[row * KP2 + col] = h;
        H3lo[row * KP2 + col] = f2bf(hv - bf2f(h));
      }
    }
  }
  __syncthreads();

#pragma unroll
  for (int sp = 0; sp < 2; sp++) {
    int strip = w + sp * 4;
    int col = strip * 16 + r16;
    float bias2 = bd2[col];
    const unsigned short* b2h = B2hi + col * KP2 + quad * 8;
    const unsigned short* b2l = B2lo + col * KP2 + quad * 8;
    bf16x8 bh0 = *(const bf16x8*)(b2h);
    bf16x8 bh1 = *(const bf16x8*)(b2h + 32);
    bf16x8 bl0 = *(const bf16x8*)(b2l);
    bf16x8 bl1 = *(const bf16x8*)(b2l + 32);
#pragma unroll
    for (int m = 0; m < 4; m++) {
      const unsigned short* ahp = H3hi + (m * 16 + r16) * KP2 + quad * 8;
      const unsigned short* alp = H3lo + (m * 16 + r16) * KP2 + quad * 8;
      bf16x8 ah0 = *(const bf16x8*)(ahp);
      bf16x8 ah1 = *(const bf16x8*)(ahp + 32);
      bf16x8 al0 = *(const bf16x8*)(alp);
      bf16x8 al1 = *(const bf16x8*)(alp + 32);
      f32x4 acc = {0.f, 0.f, 0.f, 0.f};
      acc = __builtin_amdgcn_mfma_f32_16x16x32_bf16(ah0, bh0, acc, 0, 0, 0);
      acc = __builtin_amdgcn_mfma_f32_16x16x32_bf16(ah1, bh1, acc, 0, 0, 0);
      acc = __builtin_amdgcn_mfma_f32_16x16x32_bf16(ah0, bl0, acc, 0, 0, 0);
      acc = __builtin_amdgcn_mfma_f32_16x16x32_bf16(ah1, bl1, acc, 0, 0, 0);
      acc = __builtin_amdgcn_mfma_f32_16x16x32_bf16(al0, bh0, acc, 0, 0, 0);
      acc = __builtin_amdgcn_mfma_f32_16x16x32_bf16(al1, bh1, acc, 0, 0, 0);
#pragma unroll
      for (int r = 0; r < 4; r++) {
        int n = node0 + m * 16 + quad * 4 + r;
        if (n < N_NODES) RECON[(size_t)n * 128 + col] = acc[r] + bias2;
      }
    }
  }
}

// ---------------- launch ----------------

extern "C" void kernel_launch(void* const* d_in, const int* in_sizes, int n_in,
                              void* d_out, int out_size, void* d_ws, size_t ws_size,
                              hipStream_t stream) {
  const float* x    = (const float*)d_in[0];
  const int*   eidx = (const int*)d_in[1];     // int32 per harness contract
  const int*   esrc = eidx;                    // edge_index[0]
  const int*   edst = eidx + N_EDGES;          // edge_index[1]
  const float* W1  = (const float*)d_in[2];
  const float* b1  = (const float*)d_in[3];
  const float* W2  = (const float*)d_in[4];
  const float* b2  = (const float*)d_in[5];
  const float* Wd1 = (const float*)d_in[6];
  const float* bd1 = (const float*)d_in[7];
  const float* Wd2 = (const float*)d_in[8];
  const float* bd2 = (const float*)d_in[9];

  float* recon = (float*)d_out;                                  // [N,128]
  float* z     = (float*)d_out + (size_t)N_NODES * D_INF;        // [N,32]
  // Scratch in the dead recon region (51.2 MB, written only by k_decoder_mfma):
  //   stage [E] int2   @ +0          (12.8 MB)  -- pass-A binned edges; dead
  //                                               after k_binB, then reused as:
  //   h1_16 [N,64] bf16 @ +0         (12.8 MB)
  //   z1    [N,64] fp32 @ +12.8 MB   (25.6 MB)
  //   h2_16 [N,32] bf16 @ +38.4 MB   ( 6.4 MB)   -> total 44.8 MB < 51.2 MB
  int2*           stage = (int2*)recon;
  unsigned short* h1_16 = (unsigned short*)recon;
  float*          z1    = (float*)((char*)recon + 12800000);
  unsigned short* h2_16 = (unsigned short*)((char*)recon + 38400000);

  char* ws = (char*)d_ws;
  int*   counts  = (int*)(ws + 0);
  int*   offsets = (int*)(ws + 409600);
  int*   cursor  = (int*)(ws + 819200);
  float* dinv    = (float*)(ws + 1228800);
  int*   bsums   = (int*)(ws + 1638400);
  int*   bbase   = (int*)(ws + 1639424);
  int2*  csr8    = (int2*)(ws + 1640448);      // 12,800,000 B packed (src,w)
  unsigned short* w1hi  = (unsigned short*)(ws + 14440448);
  unsigned short* w1lo  = (unsigned short*)(ws + 14457856);
  unsigned short* w2hi  = (unsigned short*)(ws + 14475264);
  unsigned short* w2lo  = (unsigned short*)(ws + 14479872);
  unsigned short* wd1hi = (unsigned short*)(ws + 14484480);
  unsigned short* wd1lo = (unsigned short*)(ws + 14489600);
  unsigned short* wd2hi = (unsigned short*)(ws + 14494720);
  unsigned short* wd2lo = (unsigned short*)(ws + 14513152);
  int*   bcur   = (int*)(ws + 14531584);       // 196 ints (bucket cursors)
  // total ws use: 14,532,608 B

  k_zero<<<(N_NODES + 255) / 256, 256, 0, stream>>>(counts);
  k_count<<<(N_EDGES + 255) / 256, 256, 0, stream>>>(edst, counts);
  k_blocksum<<<NB, 256, 0, stream>>>(counts, bsums);
  k_scanblocks<<<1, 128, 0, stream>>>(bsums, bbase, offsets);
  k_scanchunk<<<NB, 256, 0, stream>>>(counts, bbase, offsets, cursor, dinv);
  k_initbcur<<<1, 256, 0, stream>>>(offsets, bcur);
  k_binA<<<ABLOCKS, 256, 0, stream>>>(esrc, edst, bcur, stage);
  k_binB<<<NBKT * SPLITB, 256, 0, stream>>>(stage, offsets, cursor, dinv, csr8);
  k_prep_w<<<4, 256, 0, stream>>>(W1, W2, Wd1, Wd2, w1hi, w1lo, w2hi, w2lo,
                                  wd1hi, wd1lo, wd2hi, wd2lo);

  // h1 = x @ W1  (bf16 out)  -- overwrites stage (dead after k_binB)
  k_mfma_gemm<64, 128, 64><<<(N_NODES + 63) / 64, 256, 0, stream>>>(x, w1hi, w1lo, h1_16);
  // z1 = relu(agg(h1) + b1)  (fp32 out)
  k_aggregate<64, true><<<(N_NODES + 3) / 4, 256, 0, stream>>>(h1_16, offsets, csr8, dinv, b1, z1);
  // h2 = z1 @ W2  (bf16 out)
  k_mfma_gemm<64, 64, 32><<<(N_NODES + 63) / 64, 256, 0, stream>>>(z1, w2hi, w2lo, h2_16);
  // z = agg(h2) + b2  (latent output, fp32)
  k_aggregate<32, false><<<(N_NODES + 3) / 4, 256, 0, stream>>>(h2_16, offsets, csr8, dinv, b2, z);
  // recon = relu(z@Wd1+bd1) @ Wd2 + bd2
  k_decoder_mfma<<<(N_NODES + 63) / 64, 256, 0, stream>>>(z, wd1hi, wd1lo, bd1,
                                                          wd2hi, wd2lo, bd2, recon);
}

// Round 3
// 344.798 us; speedup vs baseline: 1.3784x; 1.1361x over previous
//
#include <hip/hip_runtime.h>
#include <stdint.h>

#define N_NODES 100000
#define N_EDGES 1600000
#define D_INF   128
#define D_HID   64
#define D_LAT   32
#define NB      98      // ceil(N_NODES/1024)

typedef __attribute__((ext_vector_type(8))) short bf16x8;
typedef __attribute__((ext_vector_type(4))) float f32x4;

__device__ __forceinline__ unsigned short f2bf(float v) {
  union { float f; unsigned int u; } x; x.f = v;
  unsigned int u = x.u + 0x7FFF + ((x.u >> 16) & 1);   // RNE
  return (unsigned short)(u >> 16);
}
__device__ __forceinline__ float bf2f(unsigned short h) {
  union { unsigned int u; float f; } x; x.u = ((unsigned int)h) << 16;
  return x.f;
}

// ---------------- binned CSR build (round 8: count inside buckets) ----------------
// k_binA bins (src,dst) by dst>>9 into fixed-capacity bucket regions (no
// per-node info needed). k_countB histograms each L2-resident bucket in LDS
// -> counts[] coalesced, replacing the 1.6M-global-atomic k_count (65 us).

#define NBKT      196    // ceil(100000 / 512)
#define BKT_SHIFT 9      // 512 nodes per bucket
#define BKT_CAP   10240  // fixed region capacity (mean 8192, sigma ~90)
#define EPB       4096   // edges per pass-A block
#define ABLOCKS   391    // ceil(1600000 / 4096)
#define SPLITB    4      // pass-B blocks per bucket

__global__ void k_zerobkt(int* __restrict__ bkcnt) {
  int t = threadIdx.x;
  if (t < NBKT) bkcnt[t] = 0;
}

__global__ __launch_bounds__(256) void k_binA(const int* __restrict__ esrc,
                                              const int* __restrict__ edst,
                                              int* __restrict__ bkcnt,
                                              int2* __restrict__ stage) {
  __shared__ int cnt[NBKT];
  __shared__ int sc[256];
  __shared__ int garel[NBKT];
  __shared__ int pos[NBKT];
  __shared__ __align__(16) int2 stg[EPB];   // 32 KB
  __shared__ int gaddr[EPB];                // 16 KB
  int t = threadIdx.x;
  int e0 = blockIdx.x * EPB;

  for (int i = t; i < NBKT; i += 256) cnt[i] = 0;
  __syncthreads();

  // load 16 edges/thread into registers (coalesced int4)
  int ds[16], ss[16];
  const int4* s4 = (const int4*)esrc;
  const int4* d4 = (const int4*)edst;
#pragma unroll
  for (int i = 0; i < 4; i++) {
    int idx4 = (e0 >> 2) + i * 256 + t;
    int4 dd = make_int4(-1, -1, -1, -1);
    int4 sv = make_int4(0, 0, 0, 0);
    if (idx4 < N_EDGES / 4) { dd = d4[idx4]; sv = s4[idx4]; }
    ds[i*4+0] = dd.x; ds[i*4+1] = dd.y; ds[i*4+2] = dd.z; ds[i*4+3] = dd.w;
    ss[i*4+0] = sv.x; ss[i*4+1] = sv.y; ss[i*4+2] = sv.z; ss[i*4+3] = sv.w;
  }
#pragma unroll
  for (int j = 0; j < 16; j++)
    if (ds[j] >= 0) atomicAdd(&cnt[ds[j] >> BKT_SHIFT], 1);
  __syncthreads();

  // block-level exclusive prefix over bucket counts
  int c = (t < NBKT) ? cnt[t] : 0;
  sc[t] = c;
  __syncthreads();
  int incl = c;
#pragma unroll
  for (int off = 1; off < 256; off <<= 1) {
    int x = (t >= off) ? sc[t - off] : 0;
    __syncthreads();
    incl += x;
    sc[t] = incl;
    __syncthreads();
  }
  if (t < NBKT) {
    int lb = incl - c;                                       // local base
    int gb = 0;
    if (c > 0) gb = t * BKT_CAP + atomicAdd(&bkcnt[t], c);   // reserve run
    garel[t] = gb - lb;
    pos[t]   = lb;
  }
  __syncthreads();

  // place into LDS staging in bucket order; remember global address
#pragma unroll
  for (int j = 0; j < 16; j++) {
    if (ds[j] >= 0) {
      int b  = ds[j] >> BKT_SHIFT;
      int lp = atomicAdd(&pos[b], 1);
      stg[lp]   = make_int2(ss[j], ds[j]);
      gaddr[lp] = garel[b] + lp;
    }
  }
  __syncthreads();

  // copy out: consecutive lanes -> mostly-consecutive global addresses
  int nval = N_EDGES - e0; if (nval > EPB) nval = EPB;
  for (int i = t; i < nval; i += 256)
    stage[gaddr[i]] = stg[i];
}

// per-bucket LDS histogram -> counts[] (replaces k_zero + k_count)
__global__ __launch_bounds__(256) void k_countB(const int2* __restrict__ stage,
                                                const int* __restrict__ bkcnt,
                                                int* __restrict__ counts) {
  __shared__ int hist[1 << BKT_SHIFT];
  int b = blockIdx.x;
  int t = threadIdx.x;
  for (int i = t; i < (1 << BKT_SHIFT); i += 256) hist[i] = 0;
  __syncthreads();
  int n = bkcnt[b];
  int nlo = b << BKT_SHIFT;
  const int2* reg = stage + (size_t)b * BKT_CAP;
  for (int i = t; i < n; i += 256)
    atomicAdd(&hist[reg[i].y - nlo], 1);
  __syncthreads();
  for (int i = t; i < (1 << BKT_SHIFT); i += 256) {
    int node = nlo + i;
    if (node < N_NODES) counts[node] = hist[i];
  }
}

__global__ void k_blocksum(const int* __restrict__ counts, int* __restrict__ bsums) {
  __shared__ int red[4];
  int base = blockIdx.x * 1024 + threadIdx.x * 4;
  int s = 0;
#pragma unroll
  for (int j = 0; j < 4; j++) { int i = base + j; if (i < N_NODES) s += counts[i]; }
#pragma unroll
  for (int off = 32; off > 0; off >>= 1) s += __shfl_down(s, off, 64);
  if ((threadIdx.x & 63) == 0) red[threadIdx.x >> 6] = s;
  __syncthreads();
  if (threadIdx.x == 0) bsums[blockIdx.x] = red[0] + red[1] + red[2] + red[3];
}

__global__ void k_scanblocks(const int* __restrict__ bsums, int* __restrict__ bbase,
                             int* __restrict__ offsets) {
  __shared__ int sh[128];
  int t = threadIdx.x;
  int v = (t < NB) ? bsums[t] : 0;
  sh[t] = v;
  __syncthreads();
  int incl = v;
#pragma unroll
  for (int off = 1; off < 128; off <<= 1) {
    int x = (t >= off) ? sh[t - off] : 0;
    __syncthreads();
    incl += x;
    sh[t] = incl;
    __syncthreads();
  }
  if (t < NB) bbase[t] = incl - v;
  if (t == NB - 1) offsets[N_NODES] = incl;   // == N_EDGES
}

__global__ void k_scanchunk(const int* __restrict__ counts, const int* __restrict__ bbase,
                            int* __restrict__ offsets, int* __restrict__ cursor,
                            float* __restrict__ dinv) {
  __shared__ int sh[256];
  int b = blockIdx.x, t = threadIdx.x;
  int base = b * 1024 + t * 4;
  int v[4]; int s = 0;
#pragma unroll
  for (int j = 0; j < 4; j++) { v[j] = (base + j < N_NODES) ? counts[base + j] : 0; s += v[j]; }
  sh[t] = s;
  __syncthreads();
  int incl = s;
#pragma unroll
  for (int off = 1; off < 256; off <<= 1) {
    int x = (t >= off) ? sh[t - off] : 0;
    __syncthreads();
    incl += x;
    sh[t] = incl;
    __syncthreads();
  }
  int run = bbase[b] + incl - s;
#pragma unroll
  for (int j = 0; j < 4; j++) {
    int i = base + j;
    if (i < N_NODES) {
      offsets[i] = run;
      cursor[i]  = run;
      dinv[i]    = rsqrtf((float)(v[j] + 1));   // deg = in-count + self-loop
      run += v[j];
    }
  }
}

__global__ __launch_bounds__(256) void k_binB(const int2* __restrict__ stage,
                                              const int* __restrict__ bkcnt,
                                              int* __restrict__ cursor,
                                              const float* __restrict__ dinv,
                                              int2* __restrict__ csr8) {
  int b   = blockIdx.x / SPLITB;
  int sub = blockIdx.x % SPLITB;
  int n = bkcnt[b];
  const int2* reg = stage + (size_t)b * BKT_CAP;
  for (int i = sub * 256 + threadIdx.x; i < n; i += SPLITB * 256) {
    int2 e = reg[i];
    int slot = atomicAdd(&cursor[e.y], 1);
    float w = dinv[e.x] * dinv[e.y];
    csr8[slot] = make_int2(e.x, __float_as_int(w));
  }
}

// ---------------- weight prep: W[K][M] fp32 -> Bt[col][k] bf16 hi/lo ----------------

__global__ void k_prep_w(const float* __restrict__ W1, const float* __restrict__ W2,
                         const float* __restrict__ Wd1, const float* __restrict__ Wd2,
                         unsigned short* __restrict__ w1hi, unsigned short* __restrict__ w1lo,
                         unsigned short* __restrict__ w2hi, unsigned short* __restrict__ w2lo,
                         unsigned short* __restrict__ wd1hi, unsigned short* __restrict__ wd1lo,
                         unsigned short* __restrict__ wd2hi, unsigned short* __restrict__ wd2lo) {
  const float* src; unsigned short *hi, *lo; int K, M;
  switch (blockIdx.x) {
    case 0:  src = W1;  hi = w1hi;  lo = w1lo;  K = 128; M = 64;  break;
    case 1:  src = W2;  hi = w2hi;  lo = w2lo;  K = 64;  M = 32;  break;
    case 2:  src = Wd1; hi = wd1hi; lo = wd1lo; K = 32;  M = 64;  break;
    default: src = Wd2; hi = wd2hi; lo = wd2lo; K = 64;  M = 128; break;
  }
  int KP = K + 8;
  for (int i = threadIdx.x; i < K * M; i += 256) {
    int k = i / M, c = i % M;
    float v = src[i];
    unsigned short h = f2bf(v);
    hi[c * KP + k] = h;
    lo[c * KP + k] = f2bf(v - bf2f(h));
  }
}

// ---------------- MFMA GEMM: Y[N,M] = X[N,K] @ W[K,M], fp32 in, bf16 out ----------------

template<int NODES, int K, int M>
__global__ __launch_bounds__(256) void k_mfma_gemm(const float* __restrict__ X,
                                                   const unsigned short* __restrict__ Bhi,
                                                   const unsigned short* __restrict__ Blo,
                                                   unsigned short* __restrict__ Y16) {
  constexpr int KP     = K + 8;
  constexpr int NSTRIP = M / 16;
  constexpr int KSTEPS = K / 32;
  constexpr int MTW    = (NODES / 16) * NSTRIP / 4;
  __shared__ __align__(16) unsigned short Ahi[NODES * KP];
  __shared__ __align__(16) unsigned short Alo[NODES * KP];

  int t = threadIdx.x;
  int node0 = blockIdx.x * NODES;

  for (int i = t; i < NODES * K / 4; i += 256) {
    int n = i / (K / 4), f4 = i % (K / 4);
    float4 v = make_float4(0.f, 0.f, 0.f, 0.f);
    if (node0 + n < N_NODES) v = ((const float4*)(X + (size_t)(node0 + n) * K))[f4];
    int base = n * KP + f4 * 4;
    float vv[4] = {v.x, v.y, v.z, v.w};
#pragma unroll
    for (int j = 0; j < 4; j++) {
      unsigned short h = f2bf(vv[j]);
      Ahi[base + j] = h;
      Alo[base + j] = f2bf(vv[j] - bf2f(h));
    }
  }
  __syncthreads();

  int w = t >> 6, lane = t & 63;
  int quad = lane >> 4, r16 = lane & 15;
  int strip = w % NSTRIP;

  bf16x8 bh[KSTEPS], bl[KSTEPS];
  const unsigned short* bp = Bhi + (strip * 16 + r16) * KP + quad * 8;
  const unsigned short* bq = Blo + (strip * 16 + r16) * KP + quad * 8;
#pragma unroll
  for (int ks = 0; ks < KSTEPS; ks++) {
    bh[ks] = *(const bf16x8*)(bp + ks * 32);
    bl[ks] = *(const bf16x8*)(bq + ks * 32);
  }

#pragma unroll
  for (int c = 0; c < MTW; c++) {
    int mt = (w / NSTRIP) * MTW + c;
    f32x4 acc = {0.f, 0.f, 0.f, 0.f};
    const unsigned short* ap = &Ahi[(mt * 16 + r16) * KP + quad * 8];
    const unsigned short* aq = &Alo[(mt * 16 + r16) * KP + quad * 8];
#pragma unroll
    for (int ks = 0; ks < KSTEPS; ks++) {
      bf16x8 ah = *(const bf16x8*)(ap + ks * 32);
      bf16x8 al = *(const bf16x8*)(aq + ks * 32);
      acc = __builtin_amdgcn_mfma_f32_16x16x32_bf16(ah, bh[ks], acc, 0, 0, 0);
      acc = __builtin_amdgcn_mfma_f32_16x16x32_bf16(ah, bl[ks], acc, 0, 0, 0);
      acc = __builtin_amdgcn_mfma_f32_16x16x32_bf16(al, bh[ks], acc, 0, 0, 0);
    }
    int gn  = node0 + mt * 16 + quad * 4;
    int col = strip * 16 + r16;
#pragma unroll
    for (int r = 0; r < 4; r++) {
      if (gn + r < N_NODES) Y16[(size_t)(gn + r) * M + col] = f2bf(acc[r]);
    }
  }
}

// ---------------- aggregation (gather side, multi-edge wave gathers) ----------------

template<int FEAT, bool RELU>
__global__ __launch_bounds__(256) void k_aggregate(const unsigned short* __restrict__ H16,
                            const int* __restrict__ offsets,
                            const int2* __restrict__ csr8,
                            const float* __restrict__ dinv, const float* __restrict__ bias,
                            float* __restrict__ OUT) {
  constexpr int LPG    = FEAT / 4;   // lanes per edge-group (16 or 8)
  constexpr int GROUPS = 64 / LPG;   // edges gathered per wave instr (4 or 8)

  int node = blockIdx.x * 4 + (threadIdx.x >> 6);
  int lane = threadIdx.x & 63;
  if (node >= N_NODES) return;
  int beg = offsets[node], end = offsets[node + 1];
  int g  = lane / LPG;               // which edge of the batch
  int f4 = lane % LPG;               // which feature quad

  float a0 = 0.f, a1 = 0.f, a2 = 0.f, a3 = 0.f;

  int p = beg;
  for (; p + 2 * GROUPS <= end; p += 2 * GROUPS) {
    int2 e0 = csr8[p + g];
    int2 e1 = csr8[p + GROUPS + g];
    ushort4 h0 = *(const ushort4*)(H16 + (size_t)e0.x * FEAT + f4 * 4);
    ushort4 h1 = *(const ushort4*)(H16 + (size_t)e1.x * FEAT + f4 * 4);
    float w0 = __int_as_float(e0.y), w1 = __int_as_float(e1.y);
    a0 += bf2f(h0.x) * w0; a1 += bf2f(h0.y) * w0;
    a2 += bf2f(h0.z) * w0; a3 += bf2f(h0.w) * w0;
    a0 += bf2f(h1.x) * w1; a1 += bf2f(h1.y) * w1;
    a2 += bf2f(h1.z) * w1; a3 += bf2f(h1.w) * w1;
  }
  for (; p < end; p += GROUPS) {
    int q = p + g;
    int2 e = (q < end) ? csr8[q] : make_int2(node, 0);
    ushort4 h = *(const ushort4*)(H16 + (size_t)e.x * FEAT + f4 * 4);
    float w = __int_as_float(e.y);
    a0 += bf2f(h.x) * w; a1 += bf2f(h.y) * w;
    a2 += bf2f(h.z) * w; a3 += bf2f(h.w) * w;
  }

#pragma unroll
  for (int off = LPG; off < 64; off <<= 1) {
    a0 += __shfl_xor(a0, off, 64);
    a1 += __shfl_xor(a1, off, 64);
    a2 += __shfl_xor(a2, off, 64);
    a3 += __shfl_xor(a3, off, 64);
  }

  if (g == 0) {
    float di = dinv[node];
    float sw = di * di;                         // self-loop weight
    ushort4 hs = *(const ushort4*)(H16 + (size_t)node * FEAT + f4 * 4);
    float4 bv = *(const float4*)(bias + f4 * 4);
    a0 += bf2f(hs.x) * sw + bv.x;
    a1 += bf2f(hs.y) * sw + bv.y;
    a2 += bf2f(hs.z) * sw + bv.z;
    a3 += bf2f(hs.w) * sw + bv.w;
    if (RELU) {
      a0 = fmaxf(a0, 0.f); a1 = fmaxf(a1, 0.f);
      a2 = fmaxf(a2, 0.f); a3 = fmaxf(a3, 0.f);
    }
    float4 o; o.x = a0; o.y = a1; o.z = a2; o.w = a3;
    *(float4*)(OUT + (size_t)node * FEAT + f4 * 4) = o;
  }
}

// ---------------- decoder: fused 2-stage MFMA ----------------

__global__ __launch_bounds__(256) void k_decoder_mfma(
    const float* __restrict__ Z,
    const unsigned short* __restrict__ B1hi, const unsigned short* __restrict__ B1lo,
    const float* __restrict__ bd1,
    const unsigned short* __restrict__ B2hi, const unsigned short* __restrict__ B2lo,
    const float* __restrict__ bd2, float* __restrict__ RECON) {
  constexpr int KP1 = 40;   // 32+8
  constexpr int KP2 = 72;   // 64+8
  __shared__ __align__(16) unsigned short Azhi[64 * KP1];
  __shared__ __align__(16) unsigned short Azlo[64 * KP1];
  __shared__ __align__(16) unsigned short H3hi[64 * KP2];
  __shared__ __align__(16) unsigned short H3lo[64 * KP2];
  int t = threadIdx.x;
  int node0 = blockIdx.x * 64;

  for (int i = t; i < 512; i += 256) {
    int n = i >> 3, f4 = i & 7;
    float4 v = make_float4(0.f, 0.f, 0.f, 0.f);
    if (node0 + n < N_NODES) v = ((const float4*)(Z + (size_t)(node0 + n) * 32))[f4];
    int base = n * KP1 + f4 * 4;
    float vv[4] = {v.x, v.y, v.z, v.w};
#pragma unroll
    for (int j = 0; j < 4; j++) {
      unsigned short h = f2bf(vv[j]);
      Azhi[base + j] = h;
      Azlo[base + j] = f2bf(vv[j] - bf2f(h));
    }
  }
  __syncthreads();

  int w = t >> 6, lane = t & 63;
  int quad = lane >> 4, r16 = lane & 15;

  {
    int col = w * 16 + r16;
    float bias1 = bd1[col];
    bf16x8 bh = *(const bf16x8*)(B1hi + col * KP1 + quad * 8);
    bf16x8 bl = *(const bf16x8*)(B1lo + col * KP1 + quad * 8);
#pragma unroll
    for (int m = 0; m < 4; m++) {
      bf16x8 ah = *(const bf16x8*)(Azhi + (m * 16 + r16) * KP1 + quad * 8);
      bf16x8 al = *(const bf16x8*)(Azlo + (m * 16 + r16) * KP1 + quad * 8);
      f32x4 acc = {0.f, 0.f, 0.f, 0.f};
      acc = __builtin_amdgcn_mfma_f32_16x16x32_bf16(ah, bh, acc, 0, 0, 0);
      acc = __builtin_amdgcn_mfma_f32_16x16x32_bf16(ah, bl, acc, 0, 0, 0);
      acc = __builtin_amdgcn_mfma_f32_16x16x32_bf16(al, bh, acc, 0, 0, 0);
#pragma unroll
      for (int r = 0; r < 4; r++) {
        int row = m * 16 + quad * 4 + r;
        float hv = fmaxf(acc[r] + bias1, 0.f);
        unsigned short h = f2bf(hv);
        H3hi[row * KP2 + col] = h;
        H3lo[row * KP2 + col] = f2bf(hv - bf2f(h));
      }
    }
  }
  __syncthreads();

#pragma unroll
  for (int sp = 0; sp < 2; sp++) {
    int strip = w + sp * 4;
    int col = strip * 16 + r16;
    float bias2 = bd2[col];
    const unsigned short* b2h = B2hi + col * KP2 + quad * 8;
    const unsigned short* b2l = B2lo + col * KP2 + quad * 8;
    bf16x8 bh0 = *(const bf16x8*)(b2h);
    bf16x8 bh1 = *(const bf16x8*)(b2h + 32);
    bf16x8 bl0 = *(const bf16x8*)(b2l);
    bf16x8 bl1 = *(const bf16x8*)(b2l + 32);
#pragma unroll
    for (int m = 0; m < 4; m++) {
      const unsigned short* ahp = H3hi + (m * 16 + r16) * KP2 + quad * 8;
      const unsigned short* alp = H3lo + (m * 16 + r16) * KP2 + quad * 8;
      bf16x8 ah0 = *(const bf16x8*)(ahp);
      bf16x8 ah1 = *(const bf16x8*)(ahp + 32);
      bf16x8 al0 = *(const bf16x8*)(alp);
      bf16x8 al1 = *(const bf16x8*)(alp + 32);
      f32x4 acc = {0.f, 0.f, 0.f, 0.f};
      acc = __builtin_amdgcn_mfma_f32_16x16x32_bf16(ah0, bh0, acc, 0, 0, 0);
      acc = __builtin_amdgcn_mfma_f32_16x16x32_bf16(ah1, bh1, acc, 0, 0, 0);
      acc = __builtin_amdgcn_mfma_f32_16x16x32_bf16(ah0, bl0, acc, 0, 0, 0);
      acc = __builtin_amdgcn_mfma_f32_16x16x32_bf16(ah1, bl1, acc, 0, 0, 0);
      acc = __builtin_amdgcn_mfma_f32_16x16x32_bf16(al0, bh0, acc, 0, 0, 0);
      acc = __builtin_amdgcn_mfma_f32_16x16x32_bf16(al1, bh1, acc, 0, 0, 0);
#pragma unroll
      for (int r = 0; r < 4; r++) {
        int n = node0 + m * 16 + quad * 4 + r;
        if (n < N_NODES) RECON[(size_t)n * 128 + col] = acc[r] + bias2;
      }
    }
  }
}

// ---------------- launch ----------------

extern "C" void kernel_launch(void* const* d_in, const int* in_sizes, int n_in,
                              void* d_out, int out_size, void* d_ws, size_t ws_size,
                              hipStream_t stream) {
  const float* x    = (const float*)d_in[0];
  const int*   eidx = (const int*)d_in[1];     // int32 per harness contract
  const int*   esrc = eidx;                    // edge_index[0]
  const int*   edst = eidx + N_EDGES;          // edge_index[1]
  const float* W1  = (const float*)d_in[2];
  const float* b1  = (const float*)d_in[3];
  const float* W2  = (const float*)d_in[4];
  const float* b2  = (const float*)d_in[5];
  const float* Wd1 = (const float*)d_in[6];
  const float* bd1 = (const float*)d_in[7];
  const float* Wd2 = (const float*)d_in[8];
  const float* bd2 = (const float*)d_in[9];

  float* recon = (float*)d_out;                                  // [N,128]
  float* z     = (float*)d_out + (size_t)N_NODES * D_INF;        // [N,32]
  // Scratch in the dead recon region (51.2 MB, written only by k_decoder_mfma):
  //   stage [196*10240] int2 @ +0    (16.06 MB) -- binned edges; dead after
  //                                               k_binB, region then reused:
  //   h1_16 [N,64] bf16 @ +0         (12.8 MB)
  //   z1    [N,64] fp32 @ +12.8 MB   (25.6 MB)
  //   h2_16 [N,32] bf16 @ +38.4 MB   ( 6.4 MB)   -> total 44.8 MB < 51.2 MB
  int2*           stage = (int2*)recon;
  unsigned short* h1_16 = (unsigned short*)recon;
  float*          z1    = (float*)((char*)recon + 12800000);
  unsigned short* h2_16 = (unsigned short*)((char*)recon + 38400000);

  char* ws = (char*)d_ws;
  int*   counts  = (int*)(ws + 0);
  int*   offsets = (int*)(ws + 409600);
  int*   cursor  = (int*)(ws + 819200);
  float* dinv    = (float*)(ws + 1228800);
  int*   bsums   = (int*)(ws + 1638400);
  int*   bbase   = (int*)(ws + 1639424);
  int2*  csr8    = (int2*)(ws + 1640448);      // 12,800,000 B packed (src,w)
  unsigned short* w1hi  = (unsigned short*)(ws + 14440448);
  unsigned short* w1lo  = (unsigned short*)(ws + 14457856);
  unsigned short* w2hi  = (unsigned short*)(ws + 14475264);
  unsigned short* w2lo  = (unsigned short*)(ws + 14479872);
  unsigned short* wd1hi = (unsigned short*)(ws + 14484480);
  unsigned short* wd1lo = (unsigned short*)(ws + 14489600);
  unsigned short* wd2hi = (unsigned short*)(ws + 14494720);
  unsigned short* wd2lo = (unsigned short*)(ws + 14513152);
  int*   bkcnt  = (int*)(ws + 14531584);       // 196 ints (bucket fill counts)
  // total ws use: 14,532,368 B

  k_zerobkt<<<1, 256, 0, stream>>>(bkcnt);
  k_binA<<<ABLOCKS, 256, 0, stream>>>(esrc, edst, bkcnt, stage);
  k_countB<<<NBKT, 256, 0, stream>>>(stage, bkcnt, counts);
  k_blocksum<<<NB, 256, 0, stream>>>(counts, bsums);
  k_scanblocks<<<1, 128, 0, stream>>>(bsums, bbase, offsets);
  k_scanchunk<<<NB, 256, 0, stream>>>(counts, bbase, offsets, cursor, dinv);
  k_binB<<<NBKT * SPLITB, 256, 0, stream>>>(stage, bkcnt, cursor, dinv, csr8);
  k_prep_w<<<4, 256, 0, stream>>>(W1, W2, Wd1, Wd2, w1hi, w1lo, w2hi, w2lo,
                                  wd1hi, wd1lo, wd2hi, wd2lo);

  // h1 = x @ W1  (bf16 out)  -- overwrites stage (dead after k_binB)
  k_mfma_gemm<64, 128, 64><<<(N_NODES + 63) / 64, 256, 0, stream>>>(x, w1hi, w1lo, h1_16);
  // z1 = relu(agg(h1) + b1)  (fp32 out)
  k_aggregate<64, true><<<(N_NODES + 3) / 4, 256, 0, stream>>>(h1_16, offsets, csr8, dinv, b1, z1);
  // h2 = z1 @ W2  (bf16 out)
  k_mfma_gemm<64, 64, 32><<<(N_NODES + 63) / 64, 256, 0, stream>>>(z1, w2hi, w2lo, h2_16);
  // z = agg(h2) + b2  (latent output, fp32)
  k_aggregate<32, false><<<(N_NODES + 3) / 4, 256, 0, stream>>>(h2_16, offsets, csr8, dinv, b2, z);
  // recon = relu(z@Wd1+bd1) @ Wd2 + bd2
  k_decoder_mfma<<<(N_NODES + 63) / 64, 256, 0, stream>>>(z, wd1hi, wd1lo, bd1,
                                                          wd2hi, wd2lo, bd2, recon);
}

// Round 5
// 324.716 us; speedup vs baseline: 1.4636x; 1.0618x over previous
//
#include <hip/hip_runtime.h>
#include <stdint.h>

#define N_NODES 100000
#define N_EDGES 1600000
#define D_INF   128
#define D_HID   64
#define D_LAT   32
#define NB      98      // ceil(N_NODES/1024)

typedef __attribute__((ext_vector_type(8))) short bf16x8;
typedef __attribute__((ext_vector_type(4))) float f32x4;
typedef __attribute__((ext_vector_type(8))) unsigned short u16x8;

__device__ __forceinline__ unsigned short f2bf(float v) {
  union { float f; unsigned int u; } x; x.f = v;
  unsigned int u = x.u + 0x7FFF + ((x.u >> 16) & 1);   // RNE
  return (unsigned short)(u >> 16);
}
__device__ __forceinline__ float bf2f(unsigned short h) {
  union { unsigned int u; float f; } x; x.u = ((unsigned int)h) << 16;
  return x.f;
}

// ---------------- binned CSR build ----------------
// k_binA bins (src,dst) by dst>>9 into fixed-capacity bucket regions.
// k_countB (4-way split) histograms each bucket in LDS -> counts[].

#define NBKT      196    // ceil(100000 / 512)
#define BKT_SHIFT 9      // 512 nodes per bucket
#define BKT_CAP   10240  // fixed region capacity (mean 8192, sigma ~90)
#define EPB       4096   // edges per pass-A block
#define ABLOCKS   391    // ceil(1600000 / 4096)
#define SPLITB    4      // pass-B blocks per bucket
#define SPLITC    4      // countB blocks per bucket

__global__ void k_zeroinit(int* __restrict__ counts, int* __restrict__ bkcnt) {
  int i = blockIdx.x * 256 + threadIdx.x;
  if (i < N_NODES) counts[i] = 0;
  if (blockIdx.x == 0 && threadIdx.x < NBKT) bkcnt[threadIdx.x] = 0;
}

__global__ __launch_bounds__(256) void k_binA(const int* __restrict__ esrc,
                                              const int* __restrict__ edst,
                                              int* __restrict__ bkcnt,
                                              int2* __restrict__ stage) {
  __shared__ int cnt[NBKT];
  __shared__ int sc[256];
  __shared__ int garel[NBKT];
  __shared__ int pos[NBKT];
  __shared__ __align__(16) int2 stg[EPB];   // 32 KB
  __shared__ int gaddr[EPB];                // 16 KB
  int t = threadIdx.x;
  int e0 = blockIdx.x * EPB;

  for (int i = t; i < NBKT; i += 256) cnt[i] = 0;
  __syncthreads();

  // load 16 edges/thread into registers (coalesced int4)
  int ds[16], ss[16];
  const int4* s4 = (const int4*)esrc;
  const int4* d4 = (const int4*)edst;
#pragma unroll
  for (int i = 0; i < 4; i++) {
    int idx4 = (e0 >> 2) + i * 256 + t;
    int4 dd = make_int4(-1, -1, -1, -1);
    int4 sv = make_int4(0, 0, 0, 0);
    if (idx4 < N_EDGES / 4) { dd = d4[idx4]; sv = s4[idx4]; }
    ds[i*4+0] = dd.x; ds[i*4+1] = dd.y; ds[i*4+2] = dd.z; ds[i*4+3] = dd.w;
    ss[i*4+0] = sv.x; ss[i*4+1] = sv.y; ss[i*4+2] = sv.z; ss[i*4+3] = sv.w;
  }
#pragma unroll
  for (int j = 0; j < 16; j++)
    if (ds[j] >= 0) atomicAdd(&cnt[ds[j] >> BKT_SHIFT], 1);
  __syncthreads();

  // block-level exclusive prefix over bucket counts
  int c = (t < NBKT) ? cnt[t] : 0;
  sc[t] = c;
  __syncthreads();
  int incl = c;
#pragma unroll
  for (int off = 1; off < 256; off <<= 1) {
    int x = (t >= off) ? sc[t - off] : 0;
    __syncthreads();
    incl += x;
    sc[t] = incl;
    __syncthreads();
  }
  if (t < NBKT) {
    int lb = incl - c;                                       // local base
    int gb = 0;
    if (c > 0) gb = t * BKT_CAP + atomicAdd(&bkcnt[t], c);   // reserve run
    garel[t] = gb - lb;
    pos[t]   = lb;
  }
  __syncthreads();

  // place into LDS staging in bucket order; remember global address
#pragma unroll
  for (int j = 0; j < 16; j++) {
    if (ds[j] >= 0) {
      int b  = ds[j] >> BKT_SHIFT;
      int lp = atomicAdd(&pos[b], 1);
      stg[lp]   = make_int2(ss[j], ds[j]);
      gaddr[lp] = garel[b] + lp;
    }
  }
  __syncthreads();

  // copy out: consecutive lanes -> mostly-consecutive global addresses
  int nval = N_EDGES - e0; if (nval > EPB) nval = EPB;
  for (int i = t; i < nval; i += 256)
    stage[gaddr[i]] = stg[i];
}

// per-bucket LDS histogram -> counts[] (4 sub-blocks/bucket, atomic merge)
__global__ __launch_bounds__(256) void k_countB(const int2* __restrict__ stage,
                                                const int* __restrict__ bkcnt,
                                                int* __restrict__ counts) {
  __shared__ int hist[1 << BKT_SHIFT];
  int b   = blockIdx.x / SPLITC;
  int sub = blockIdx.x % SPLITC;
  int t = threadIdx.x;
  for (int i = t; i < (1 << BKT_SHIFT); i += 256) hist[i] = 0;
  __syncthreads();
  int n = bkcnt[b];
  int nlo = b << BKT_SHIFT;
  const int2* reg = stage + (size_t)b * BKT_CAP;
  for (int i = sub * 256 + t; i < n; i += SPLITC * 256)
    atomicAdd(&hist[reg[i].y - nlo], 1);
  __syncthreads();
  for (int i = t; i < (1 << BKT_SHIFT); i += 256) {
    int node = nlo + i;
    if (node < N_NODES) {
      int v = hist[i];
      if (v) atomicAdd(&counts[node], v);
    }
  }
}

__global__ void k_blocksum(const int* __restrict__ counts, int* __restrict__ bsums) {
  __shared__ int red[4];
  int base = blockIdx.x * 1024 + threadIdx.x * 4;
  int s = 0;
#pragma unroll
  for (int j = 0; j < 4; j++) { int i = base + j; if (i < N_NODES) s += counts[i]; }
#pragma unroll
  for (int off = 32; off > 0; off >>= 1) s += __shfl_down(s, off, 64);
  if ((threadIdx.x & 63) == 0) red[threadIdx.x >> 6] = s;
  __syncthreads();
  if (threadIdx.x == 0) bsums[blockIdx.x] = red[0] + red[1] + red[2] + red[3];
}

__global__ void k_scanblocks(const int* __restrict__ bsums, int* __restrict__ bbase,
                             int* __restrict__ offsets) {
  __shared__ int sh[128];
  int t = threadIdx.x;
  int v = (t < NB) ? bsums[t] : 0;
  sh[t] = v;
  __syncthreads();
  int incl = v;
#pragma unroll
  for (int off = 1; off < 128; off <<= 1) {
    int x = (t >= off) ? sh[t - off] : 0;
    __syncthreads();
    incl += x;
    sh[t] = incl;
    __syncthreads();
  }
  if (t < NB) bbase[t] = incl - v;
  if (t == NB - 1) offsets[N_NODES] = incl;   // == N_EDGES
}

__global__ void k_scanchunk(const int* __restrict__ counts, const int* __restrict__ bbase,
                            int* __restrict__ offsets, int* __restrict__ cursor,
                            float* __restrict__ dinv) {
  __shared__ int sh[256];
  int b = blockIdx.x, t = threadIdx.x;
  int base = b * 1024 + t * 4;
  int v[4]; int s = 0;
#pragma unroll
  for (int j = 0; j < 4; j++) { v[j] = (base + j < N_NODES) ? counts[base + j] : 0; s += v[j]; }
  sh[t] = s;
  __syncthreads();
  int incl = s;
#pragma unroll
  for (int off = 1; off < 256; off <<= 1) {
    int x = (t >= off) ? sh[t - off] : 0;
    __syncthreads();
    incl += x;
    sh[t] = incl;
    __syncthreads();
  }
  int run = bbase[b] + incl - s;
#pragma unroll
  for (int j = 0; j < 4; j++) {
    int i = base + j;
    if (i < N_NODES) {
      offsets[i] = run;
      cursor[i]  = run;
      dinv[i]    = rsqrtf((float)(v[j] + 1));   // deg = in-count + self-loop
      run += v[j];
    }
  }
}

__global__ __launch_bounds__(256) void k_binB(const int2* __restrict__ stage,
                                              const int* __restrict__ bkcnt,
                                              int* __restrict__ cursor,
                                              const float* __restrict__ dinv,
                                              int2* __restrict__ csr8) {
  int b   = blockIdx.x / SPLITB;
  int sub = blockIdx.x % SPLITB;
  int n = bkcnt[b];
  const int2* reg = stage + (size_t)b * BKT_CAP;
  for (int i = sub * 256 + threadIdx.x; i < n; i += SPLITB * 256) {
    int2 e = reg[i];
    int slot = atomicAdd(&cursor[e.y], 1);
    float w = dinv[e.x] * dinv[e.y];
    csr8[slot] = make_int2(e.x, __float_as_int(w));
  }
}

// ---------------- weight prep: W[K][M] fp32 -> Bt[col][k] bf16 hi/lo ----------------

__global__ void k_prep_w(const float* __restrict__ W1, const float* __restrict__ W2,
                         const float* __restrict__ Wd1, const float* __restrict__ Wd2,
                         unsigned short* __restrict__ w1hi, unsigned short* __restrict__ w1lo,
                         unsigned short* __restrict__ w2hi, unsigned short* __restrict__ w2lo,
                         unsigned short* __restrict__ wd1hi, unsigned short* __restrict__ wd1lo,
                         unsigned short* __restrict__ wd2hi, unsigned short* __restrict__ wd2lo) {
  const float* src; unsigned short *hi, *lo; int K, M;
  switch (blockIdx.x) {
    case 0:  src = W1;  hi = w1hi;  lo = w1lo;  K = 128; M = 64;  break;
    case 1:  src = W2;  hi = w2hi;  lo = w2lo;  K = 64;  M = 32;  break;
    case 2:  src = Wd1; hi = wd1hi; lo = wd1lo; K = 32;  M = 64;  break;
    default: src = Wd2; hi = wd2hi; lo = wd2lo; K = 64;  M = 128; break;
  }
  int KP = K + 8;
  for (int i = threadIdx.x; i < K * M; i += 256) {
    int k = i / M, c = i % M;
    float v = src[i];
    unsigned short h = f2bf(v);
    hi[c * KP + k] = h;
    lo[c * KP + k] = f2bf(v - bf2f(h));
  }
}

// ---------------- MFMA GEMM: Y[N,M] = X[N,K] @ W[K,M], fp32 in, bf16 out ----------------

template<int NODES, int K, int M>
__global__ __launch_bounds__(256) void k_mfma_gemm(const float* __restrict__ X,
                                                   const unsigned short* __restrict__ Bhi,
                                                   const unsigned short* __restrict__ Blo,
                                                   unsigned short* __restrict__ Y16) {
  constexpr int KP     = K + 8;
  constexpr int NSTRIP = M / 16;
  constexpr int KSTEPS = K / 32;
  constexpr int MTW    = (NODES / 16) * NSTRIP / 4;
  __shared__ __align__(16) unsigned short Ahi[NODES * KP];
  __shared__ __align__(16) unsigned short Alo[NODES * KP];

  int t = threadIdx.x;
  int node0 = blockIdx.x * NODES;

  for (int i = t; i < NODES * K / 4; i += 256) {
    int n = i / (K / 4), f4 = i % (K / 4);
    float4 v = make_float4(0.f, 0.f, 0.f, 0.f);
    if (node0 + n < N_NODES) v = ((const float4*)(X + (size_t)(node0 + n) * K))[f4];
    int base = n * KP + f4 * 4;
    float vv[4] = {v.x, v.y, v.z, v.w};
#pragma unroll
    for (int j = 0; j < 4; j++) {
      unsigned short h = f2bf(vv[j]);
      Ahi[base + j] = h;
      Alo[base + j] = f2bf(vv[j] - bf2f(h));
    }
  }
  __syncthreads();

  int w = t >> 6, lane = t & 63;
  int quad = lane >> 4, r16 = lane & 15;
  int strip = w % NSTRIP;

  bf16x8 bh[KSTEPS], bl[KSTEPS];
  const unsigned short* bp = Bhi + (strip * 16 + r16) * KP + quad * 8;
  const unsigned short* bq = Blo + (strip * 16 + r16) * KP + quad * 8;
#pragma unroll
  for (int ks = 0; ks < KSTEPS; ks++) {
    bh[ks] = *(const bf16x8*)(bp + ks * 32);
    bl[ks] = *(const bf16x8*)(bq + ks * 32);
  }

#pragma unroll
  for (int c = 0; c < MTW; c++) {
    int mt = (w / NSTRIP) * MTW + c;
    f32x4 acc = {0.f, 0.f, 0.f, 0.f};
    const unsigned short* ap = &Ahi[(mt * 16 + r16) * KP + quad * 8];
    const unsigned short* aq = &Alo[(mt * 16 + r16) * KP + quad * 8];
#pragma unroll
    for (int ks = 0; ks < KSTEPS; ks++) {
      bf16x8 ah = *(const bf16x8*)(ap + ks * 32);
      bf16x8 al = *(const bf16x8*)(aq + ks * 32);
      acc = __builtin_amdgcn_mfma_f32_16x16x32_bf16(ah, bh[ks], acc, 0, 0, 0);
      acc = __builtin_amdgcn_mfma_f32_16x16x32_bf16(ah, bl[ks], acc, 0, 0, 0);
      acc = __builtin_amdgcn_mfma_f32_16x16x32_bf16(al, bh[ks], acc, 0, 0, 0);
    }
    int gn  = node0 + mt * 16 + quad * 4;
    int col = strip * 16 + r16;
#pragma unroll
    for (int r = 0; r < 4; r++) {
      if (gn + r < N_NODES) Y16[(size_t)(gn + r) * M + col] = f2bf(acc[r]);
    }
  }
}

// ---------------- aggregation (ushort8 gathers, 8/16 edges per instr) ----------
// FEAT=64: 8 lanes/edge x 16B -> 8 edges per wave gather; 2 batches = 16 edges/iter.
// FEAT=32: 4 lanes/edge -> 16 edges per gather; 32 edges/iter. Masked tail lanes
// read the node's own (cache-hot) row with weight 0.

template<int FEAT, bool RELU>
__global__ __launch_bounds__(256) void k_aggregate(const unsigned short* __restrict__ H16,
                            const int* __restrict__ offsets,
                            const int2* __restrict__ csr8,
                            const float* __restrict__ dinv, const float* __restrict__ bias,
                            float* __restrict__ OUT) {
  constexpr int LPE    = FEAT / 8;   // lanes per edge (8 or 4)
  constexpr int GROUPS = 64 / LPE;   // edges per wave gather (8 or 16)

  int node = blockIdx.x * 4 + (threadIdx.x >> 6);
  int lane = threadIdx.x & 63;
  if (node >= N_NODES) return;
  int beg = offsets[node], end = offsets[node + 1];
  int g  = lane / LPE;               // which edge of the batch
  int f8 = lane % LPE;               // which feature octet

  float a0=0.f,a1=0.f,a2=0.f,a3=0.f,a4=0.f,a5=0.f,a6=0.f,a7=0.f;

  for (int p = beg; p < end; p += 2 * GROUPS) {
    int q0 = p + g, q1 = p + GROUPS + g;
    int2 e0 = (q0 < end) ? csr8[q0] : make_int2(node, 0);
    int2 e1 = (q1 < end) ? csr8[q1] : make_int2(node, 0);
    u16x8 h0 = *(const u16x8*)(H16 + (size_t)e0.x * FEAT + f8 * 8);
    u16x8 h1 = *(const u16x8*)(H16 + (size_t)e1.x * FEAT + f8 * 8);
    float w0 = __int_as_float(e0.y), w1 = __int_as_float(e1.y);
    a0 += bf2f(h0[0]) * w0; a1 += bf2f(h0[1]) * w0;
    a2 += bf2f(h0[2]) * w0; a3 += bf2f(h0[3]) * w0;
    a4 += bf2f(h0[4]) * w0; a5 += bf2f(h0[5]) * w0;
    a6 += bf2f(h0[6]) * w0; a7 += bf2f(h0[7]) * w0;
    a0 += bf2f(h1[0]) * w1; a1 += bf2f(h1[1]) * w1;
    a2 += bf2f(h1[2]) * w1; a3 += bf2f(h1[3]) * w1;
    a4 += bf2f(h1[4]) * w1; a5 += bf2f(h1[5]) * w1;
    a6 += bf2f(h1[6]) * w1; a7 += bf2f(h1[7]) * w1;
  }

  // fold edge-groups together (g lives in the upper lane bits)
#pragma unroll
  for (int off = LPE; off < 64; off <<= 1) {
    a0 += __shfl_xor(a0, off, 64);
    a1 += __shfl_xor(a1, off, 64);
    a2 += __shfl_xor(a2, off, 64);
    a3 += __shfl_xor(a3, off, 64);
    a4 += __shfl_xor(a4, off, 64);
    a5 += __shfl_xor(a5, off, 64);
    a6 += __shfl_xor(a6, off, 64);
    a7 += __shfl_xor(a7, off, 64);
  }

  if (g == 0) {
    float di = dinv[node];
    float sw = di * di;                         // self-loop weight
    u16x8 hs = *(const u16x8*)(H16 + (size_t)node * FEAT + f8 * 8);
    float4 bv0 = *(const float4*)(bias + f8 * 8);
    float4 bv1 = *(const float4*)(bias + f8 * 8 + 4);
    a0 += bf2f(hs[0]) * sw + bv0.x;
    a1 += bf2f(hs[1]) * sw + bv0.y;
    a2 += bf2f(hs[2]) * sw + bv0.z;
    a3 += bf2f(hs[3]) * sw + bv0.w;
    a4 += bf2f(hs[4]) * sw + bv1.x;
    a5 += bf2f(hs[5]) * sw + bv1.y;
    a6 += bf2f(hs[6]) * sw + bv1.z;
    a7 += bf2f(hs[7]) * sw + bv1.w;
    if (RELU) {
      a0 = fmaxf(a0, 0.f); a1 = fmaxf(a1, 0.f);
      a2 = fmaxf(a2, 0.f); a3 = fmaxf(a3, 0.f);
      a4 = fmaxf(a4, 0.f); a5 = fmaxf(a5, 0.f);
      a6 = fmaxf(a6, 0.f); a7 = fmaxf(a7, 0.f);
    }
    float4 o0; o0.x = a0; o0.y = a1; o0.z = a2; o0.w = a3;
    float4 o1; o1.x = a4; o1.y = a5; o1.z = a6; o1.w = a7;
    *(float4*)(OUT + (size_t)node * FEAT + f8 * 8)     = o0;
    *(float4*)(OUT + (size_t)node * FEAT + f8 * 8 + 4) = o1;
  }
}

// ---------------- decoder: fused 2-stage MFMA ----------------

__global__ __launch_bounds__(256) void k_decoder_mfma(
    const float* __restrict__ Z,
    const unsigned short* __restrict__ B1hi, const unsigned short* __restrict__ B1lo,
    const float* __restrict__ bd1,
    const unsigned short* __restrict__ B2hi, const unsigned short* __restrict__ B2lo,
    const float* __restrict__ bd2, float* __restrict__ RECON) {
  constexpr int KP1 = 40;   // 32+8
  constexpr int KP2 = 72;   // 64+8
  __shared__ __align__(16) unsigned short Azhi[64 * KP1];
  __shared__ __align__(16) unsigned short Azlo[64 * KP1];
  __shared__ __align__(16) unsigned short H3hi[64 * KP2];
  __shared__ __align__(16) unsigned short H3lo[64 * KP2];
  int t = threadIdx.x;
  int node0 = blockIdx.x * 64;

  for (int i = t; i < 512; i += 256) {
    int n = i >> 3, f4 = i & 7;
    float4 v = make_float4(0.f, 0.f, 0.f, 0.f);
    if (node0 + n < N_NODES) v = ((const float4*)(Z + (size_t)(node0 + n) * 32))[f4];
    int base = n * KP1 + f4 * 4;
    float vv[4] = {v.x, v.y, v.z, v.w};
#pragma unroll
    for (int j = 0; j < 4; j++) {
      unsigned short h = f2bf(vv[j]);
      Azhi[base + j] = h;
      Azlo[base + j] = f2bf(vv[j] - bf2f(h));
    }
  }
  __syncthreads();

  int w = t >> 6, lane = t & 63;
  int quad = lane >> 4, r16 = lane & 15;

  {
    int col = w * 16 + r16;
    float bias1 = bd1[col];
    bf16x8 bh = *(const bf16x8*)(B1hi + col * KP1 + quad * 8);
    bf16x8 bl = *(const bf16x8*)(B1lo + col * KP1 + quad * 8);
#pragma unroll
    for (int m = 0; m < 4; m++) {
      bf16x8 ah = *(const bf16x8*)(Azhi + (m * 16 + r16) * KP1 + quad * 8);
      bf16x8 al = *(const bf16x8*)(Azlo + (m * 16 + r16) * KP1 + quad * 8);
      f32x4 acc = {0.f, 0.f, 0.f, 0.f};
      acc = __builtin_amdgcn_mfma_f32_16x16x32_bf16(ah, bh, acc, 0, 0, 0);
      acc = __builtin_amdgcn_mfma_f32_16x16x32_bf16(ah, bl, acc, 0, 0, 0);
      acc = __builtin_amdgcn_mfma_f32_16x16x32_bf16(al, bh, acc, 0, 0, 0);
#pragma unroll
      for (int r = 0; r < 4; r++) {
        int row = m * 16 + quad * 4 + r;
        float hv = fmaxf(acc[r] + bias1, 0.f);
        unsigned short h = f2bf(hv);
        H3hi[row * KP2 + col] = h;
        H3lo[row * KP2 + col] = f2bf(hv - bf2f(h));
      }
    }
  }
  __syncthreads();

#pragma unroll
  for (int sp = 0; sp < 2; sp++) {
    int strip = w + sp * 4;
    int col = strip * 16 + r16;
    float bias2 = bd2[col];
    const unsigned short* b2h = B2hi + col * KP2 + quad * 8;
    const unsigned short* b2l = B2lo + col * KP2 + quad * 8;
    bf16x8 bh0 = *(const bf16x8*)(b2h);
    bf16x8 bh1 = *(const bf16x8*)(b2h + 32);
    bf16x8 bl0 = *(const bf16x8*)(b2l);
    bf16x8 bl1 = *(const bf16x8*)(b2l + 32);
#pragma unroll
    for (int m = 0; m < 4; m++) {
      const unsigned short* ahp = H3hi + (m * 16 + r16) * KP2 + quad * 8;
      const unsigned short* alp = H3lo + (m * 16 + r16) * KP2 + quad * 8;
      bf16x8 ah0 = *(const bf16x8*)(ahp);
      bf16x8 ah1 = *(const bf16x8*)(ahp + 32);
      bf16x8 al0 = *(const bf16x8*)(alp);
      bf16x8 al1 = *(const bf16x8*)(alp + 32);
      f32x4 acc = {0.f, 0.f, 0.f, 0.f};
      acc = __builtin_amdgcn_mfma_f32_16x16x32_bf16(ah0, bh0, acc, 0, 0, 0);
      acc = __builtin_amdgcn_mfma_f32_16x16x32_bf16(ah1, bh1, acc, 0, 0, 0);
      acc = __builtin_amdgcn_mfma_f32_16x16x32_bf16(ah0, bl0, acc, 0, 0, 0);
      acc = __builtin_amdgcn_mfma_f32_16x16x32_bf16(ah1, bl1, acc, 0, 0, 0);
      acc = __builtin_amdgcn_mfma_f32_16x16x32_bf16(al0, bh0, acc, 0, 0, 0);
      acc = __builtin_amdgcn_mfma_f32_16x16x32_bf16(al1, bh1, acc, 0, 0, 0);
#pragma unroll
      for (int r = 0; r < 4; r++) {
        int n = node0 + m * 16 + quad * 4 + r;
        if (n < N_NODES) RECON[(size_t)n * 128 + col] = acc[r] + bias2;
      }
    }
  }
}

// ---------------- launch ----------------

extern "C" void kernel_launch(void* const* d_in, const int* in_sizes, int n_in,
                              void* d_out, int out_size, void* d_ws, size_t ws_size,
                              hipStream_t stream) {
  const float* x    = (const float*)d_in[0];
  const int*   eidx = (const int*)d_in[1];     // int32 per harness contract
  const int*   esrc = eidx;                    // edge_index[0]
  const int*   edst = eidx + N_EDGES;          // edge_index[1]
  const float* W1  = (const float*)d_in[2];
  const float* b1  = (const float*)d_in[3];
  const float* W2  = (const float*)d_in[4];
  const float* b2  = (const float*)d_in[5];
  const float* Wd1 = (const float*)d_in[6];
  const float* bd1 = (const float*)d_in[7];
  const float* Wd2 = (const float*)d_in[8];
  const float* bd2 = (const float*)d_in[9];

  float* recon = (float*)d_out;                                  // [N,128]
  float* z     = (float*)d_out + (size_t)N_NODES * D_INF;        // [N,32]
  // Scratch in the dead recon region (51.2 MB, written only by k_decoder_mfma):
  //   stage [196*10240] int2 @ +0    (16.06 MB) -- binned edges; dead after
  //                                               k_binB, region then reused:
  //   h1_16 [N,64] bf16 @ +0         (12.8 MB)
  //   z1    [N,64] fp32 @ +12.8 MB   (25.6 MB)
  //   h2_16 [N,32] bf16 @ +38.4 MB   ( 6.4 MB)   -> total 44.8 MB < 51.2 MB
  int2*           stage = (int2*)recon;
  unsigned short* h1_16 = (unsigned short*)recon;
  float*          z1    = (float*)((char*)recon + 12800000);
  unsigned short* h2_16 = (unsigned short*)((char*)recon + 38400000);

  char* ws = (char*)d_ws;
  int*   counts  = (int*)(ws + 0);
  int*   offsets = (int*)(ws + 409600);
  int*   cursor  = (int*)(ws + 819200);
  float* dinv    = (float*)(ws + 1228800);
  int*   bsums   = (int*)(ws + 1638400);
  int*   bbase   = (int*)(ws + 1639424);
  int2*  csr8    = (int2*)(ws + 1640448);      // 12,800,000 B packed (src,w)
  unsigned short* w1hi  = (unsigned short*)(ws + 14440448);
  unsigned short* w1lo  = (unsigned short*)(ws + 14457856);
  unsigned short* w2hi  = (unsigned short*)(ws + 14475264);
  unsigned short* w2lo  = (unsigned short*)(ws + 14479872);
  unsigned short* wd1hi = (unsigned short*)(ws + 14484480);
  unsigned short* wd1lo = (unsigned short*)(ws + 14489600);
  unsigned short* wd2hi = (unsigned short*)(ws + 14494720);
  unsigned short* wd2lo = (unsigned short*)(ws + 14513152);
  int*   bkcnt  = (int*)(ws + 14531584);       // 196 ints (bucket fill counts)
  // total ws use: 14,532,368 B

  k_zeroinit<<<391, 256, 0, stream>>>(counts, bkcnt);
  k_binA<<<ABLOCKS, 256, 0, stream>>>(esrc, edst, bkcnt, stage);
  k_countB<<<NBKT * SPLITC, 256, 0, stream>>>(stage, bkcnt, counts);
  k_blocksum<<<NB, 256, 0, stream>>>(counts, bsums);
  k_scanblocks<<<1, 128, 0, stream>>>(bsums, bbase, offsets);
  k_scanchunk<<<NB, 256, 0, stream>>>(counts, bbase, offsets, cursor, dinv);
  k_binB<<<NBKT * SPLITB, 256, 0, stream>>>(stage, bkcnt, cursor, dinv, csr8);
  k_prep_w<<<4, 256, 0, stream>>>(W1, W2, Wd1, Wd2, w1hi, w1lo, w2hi, w2lo,
                                  wd1hi, wd1lo, wd2hi, wd2lo);

  // h1 = x @ W1  (bf16 out)  -- overwrites stage (dead after k_binB)
  k_mfma_gemm<64, 128, 64><<<(N_NODES + 63) / 64, 256, 0, stream>>>(x, w1hi, w1lo, h1_16);
  // z1 = relu(agg(h1) + b1)  (fp32 out)
  k_aggregate<64, true><<<(N_NODES + 3) / 4, 256, 0, stream>>>(h1_16, offsets, csr8, dinv, b1, z1);
  // h2 = z1 @ W2  (bf16 out)
  k_mfma_gemm<64, 64, 32><<<(N_NODES + 63) / 64, 256, 0, stream>>>(z1, w2hi, w2lo, h2_16);
  // z = agg(h2) + b2  (latent output, fp32)
  k_aggregate<32, false><<<(N_NODES + 3) / 4, 256, 0, stream>>>(h2_16, offsets, csr8, dinv, b2, z);
  // recon = relu(z@Wd1+bd1) @ Wd2 + bd2
  k_decoder_mfma<<<(N_NODES + 63) / 64, 256, 0, stream>>>(z, wd1hi, wd1lo, bd1,
                                                          wd2hi, wd2lo, bd2, recon);
}

// Round 6
// 289.963 us; speedup vs baseline: 1.6391x; 1.1199x over previous
//
#include <hip/hip_runtime.h>
#include <stdint.h>

#define N_NODES 100000
#define N_EDGES 1600000
#define D_INF   128
#define D_HID   64
#define D_LAT   32

typedef __attribute__((ext_vector_type(8))) short bf16x8;
typedef __attribute__((ext_vector_type(4))) float f32x4;
typedef __attribute__((ext_vector_type(8))) unsigned short u16x8;

__device__ __forceinline__ unsigned short f2bf(float v) {
  union { float f; unsigned int u; } x; x.f = v;
  unsigned int u = x.u + 0x7FFF + ((x.u >> 16) & 1);   // RNE
  return (unsigned short)(u >> 16);
}
__device__ __forceinline__ float bf2f(unsigned short h) {
  union { unsigned int u; float f; } x; x.u = ((unsigned int)h) << 16;
  return x.f;
}

// ---------------- binned CSR build (round 11: bucket-local everything) --------
// k_binA bins (src,dst) by dst>>9 into fixed-capacity bucket staging regions.
// k_csr (one block per bucket): LDS histogram + LDS scan + LDS-cursor scatter
// -> beg[], cnt[], dinv[], csr4[] (src only; dinv premultiplied into the
// feature table by the GEMM epilogue, so no per-edge weight is stored).

#define NBKT      196    // ceil(100000 / 512)
#define BKT_SHIFT 9      // 512 nodes per bucket
#define BKT_CAP   10240  // fixed region capacity (mean 8192, sigma ~90)
#define EPB       4096   // edges per pass-A block
#define ABLOCKS   391    // ceil(1600000 / 4096)

__global__ void k_zerobkt(int* __restrict__ bkcnt) {
  if (threadIdx.x < NBKT) bkcnt[threadIdx.x] = 0;
}

__global__ __launch_bounds__(256) void k_binA(const int* __restrict__ esrc,
                                              const int* __restrict__ edst,
                                              int* __restrict__ bkcnt,
                                              int2* __restrict__ stage) {
  __shared__ int cnt[NBKT];
  __shared__ int sc[256];
  __shared__ int garel[NBKT];
  __shared__ int pos[NBKT];
  __shared__ __align__(16) int2 stg[EPB];   // 32 KB
  int t = threadIdx.x;
  int e0 = blockIdx.x * EPB;

  for (int i = t; i < NBKT; i += 256) cnt[i] = 0;
  __syncthreads();

  // load 16 edges/thread into registers (coalesced int4)
  int ds[16], ss[16];
  const int4* s4 = (const int4*)esrc;
  const int4* d4 = (const int4*)edst;
#pragma unroll
  for (int i = 0; i < 4; i++) {
    int idx4 = (e0 >> 2) + i * 256 + t;
    int4 dd = make_int4(-1, -1, -1, -1);
    int4 sv = make_int4(0, 0, 0, 0);
    if (idx4 < N_EDGES / 4) { dd = d4[idx4]; sv = s4[idx4]; }
    ds[i*4+0] = dd.x; ds[i*4+1] = dd.y; ds[i*4+2] = dd.z; ds[i*4+3] = dd.w;
    ss[i*4+0] = sv.x; ss[i*4+1] = sv.y; ss[i*4+2] = sv.z; ss[i*4+3] = sv.w;
  }
#pragma unroll
  for (int j = 0; j < 16; j++)
    if (ds[j] >= 0) atomicAdd(&cnt[ds[j] >> BKT_SHIFT], 1);
  __syncthreads();

  // block-level exclusive prefix over bucket counts
  int c = (t < NBKT) ? cnt[t] : 0;
  sc[t] = c;
  __syncthreads();
  int incl = c;
#pragma unroll
  for (int off = 1; off < 256; off <<= 1) {
    int x = (t >= off) ? sc[t - off] : 0;
    __syncthreads();
    incl += x;
    sc[t] = incl;
    __syncthreads();
  }
  if (t < NBKT) {
    int lb = incl - c;                                       // local base
    int gb = 0;
    if (c > 0) gb = t * BKT_CAP + atomicAdd(&bkcnt[t], c);   // reserve run
    garel[t] = gb - lb;
    pos[t]   = lb;
  }
  __syncthreads();

  // place into LDS staging in bucket order
#pragma unroll
  for (int j = 0; j < 16; j++) {
    if (ds[j] >= 0) {
      int b  = ds[j] >> BKT_SHIFT;
      int lp = atomicAdd(&pos[b], 1);
      stg[lp] = make_int2(ss[j], ds[j]);
    }
  }
  __syncthreads();

  // copy out: global addr recovered as garel[bucket] + local index
  int nval = N_EDGES - e0; if (nval > EPB) nval = EPB;
  for (int i = t; i < nval; i += 256) {
    int2 e = stg[i];
    stage[garel[e.y >> BKT_SHIFT] + i] = e;
  }
}

// one block per bucket: histogram + scan + scatter, all bucket-local
__global__ __launch_bounds__(512) void k_csr(const int2* __restrict__ stage,
                                             const int* __restrict__ bkcnt,
                                             int* __restrict__ beg,
                                             int* __restrict__ cnt,
                                             float* __restrict__ dinv,
                                             int* __restrict__ csr4) {
  __shared__ int hist[512];
  __shared__ int scan[512];
  int b = blockIdx.x, t = threadIdx.x;
  hist[t] = 0;
  __syncthreads();
  int n = bkcnt[b];
  int nlo = b << BKT_SHIFT;
  const int2* reg = stage + (size_t)b * BKT_CAP;
  for (int i = t; i < n; i += 512)
    atomicAdd(&hist[reg[i].y - nlo], 1);
  __syncthreads();
  int v = hist[t];
  scan[t] = v;
  __syncthreads();
  int incl = v;
#pragma unroll
  for (int off = 1; off < 512; off <<= 1) {
    int x = (t >= off) ? scan[t - off] : 0;
    __syncthreads();
    incl += x;
    scan[t] = incl;
    __syncthreads();
  }
  int loc = incl - v;                    // exclusive scan
  int node = nlo + t;
  if (node < N_NODES) {
    beg[node]  = b * BKT_CAP + loc;
    cnt[node]  = v;
    dinv[node] = rsqrtf((float)(v + 1)); // deg = in-count + self-loop
  }
  scan[t] = loc;                         // reuse as cursor
  __syncthreads();
  int* c4 = csr4 + (size_t)b * BKT_CAP;
  for (int i = t; i < n; i += 512) {
    int2 e = reg[i];
    int slot = atomicAdd(&scan[e.y - nlo], 1);
    c4[slot] = e.x;
  }
}

// ---------------- weight prep: W[K][M] fp32 -> Bt[col][k] bf16 hi/lo ----------------

__global__ void k_prep_w(const float* __restrict__ W1, const float* __restrict__ W2,
                         const float* __restrict__ Wd1, const float* __restrict__ Wd2,
                         unsigned short* __restrict__ w1hi, unsigned short* __restrict__ w1lo,
                         unsigned short* __restrict__ w2hi, unsigned short* __restrict__ w2lo,
                         unsigned short* __restrict__ wd1hi, unsigned short* __restrict__ wd1lo,
                         unsigned short* __restrict__ wd2hi, unsigned short* __restrict__ wd2lo) {
  const float* src; unsigned short *hi, *lo; int K, M;
  switch (blockIdx.x) {
    case 0:  src = W1;  hi = w1hi;  lo = w1lo;  K = 128; M = 64;  break;
    case 1:  src = W2;  hi = w2hi;  lo = w2lo;  K = 64;  M = 32;  break;
    case 2:  src = Wd1; hi = wd1hi; lo = wd1lo; K = 32;  M = 64;  break;
    default: src = Wd2; hi = wd2hi; lo = wd2lo; K = 64;  M = 128; break;
  }
  int KP = K + 8;
  for (int i = threadIdx.x; i < K * M; i += 256) {
    int k = i / M, c = i % M;
    float v = src[i];
    unsigned short h = f2bf(v);
    hi[c * KP + k] = h;
    lo[c * KP + k] = f2bf(v - bf2f(h));
  }
}

// ---------------- MFMA GEMM: Y[N,M] = (X[N,K] @ W[K,M]) * dinv[n], bf16 out --------
// dinv premultiplied so the aggregate needs no per-edge weight.

template<int NODES, int K, int M>
__global__ __launch_bounds__(256) void k_mfma_gemm(const float* __restrict__ X,
                                                   const unsigned short* __restrict__ Bhi,
                                                   const unsigned short* __restrict__ Blo,
                                                   const float* __restrict__ dinv,
                                                   unsigned short* __restrict__ Y16) {
  constexpr int KP     = K + 8;
  constexpr int NSTRIP = M / 16;
  constexpr int KSTEPS = K / 32;
  constexpr int MTW    = (NODES / 16) * NSTRIP / 4;
  __shared__ __align__(16) unsigned short Ahi[NODES * KP];
  __shared__ __align__(16) unsigned short Alo[NODES * KP];

  int t = threadIdx.x;
  int node0 = blockIdx.x * NODES;

  for (int i = t; i < NODES * K / 4; i += 256) {
    int n = i / (K / 4), f4 = i % (K / 4);
    float4 v = make_float4(0.f, 0.f, 0.f, 0.f);
    if (node0 + n < N_NODES) v = ((const float4*)(X + (size_t)(node0 + n) * K))[f4];
    int base = n * KP + f4 * 4;
    float vv[4] = {v.x, v.y, v.z, v.w};
#pragma unroll
    for (int j = 0; j < 4; j++) {
      unsigned short h = f2bf(vv[j]);
      Ahi[base + j] = h;
      Alo[base + j] = f2bf(vv[j] - bf2f(h));
    }
  }
  __syncthreads();

  int w = t >> 6, lane = t & 63;
  int quad = lane >> 4, r16 = lane & 15;
  int strip = w % NSTRIP;

  bf16x8 bh[KSTEPS], bl[KSTEPS];
  const unsigned short* bp = Bhi + (strip * 16 + r16) * KP + quad * 8;
  const unsigned short* bq = Blo + (strip * 16 + r16) * KP + quad * 8;
#pragma unroll
  for (int ks = 0; ks < KSTEPS; ks++) {
    bh[ks] = *(const bf16x8*)(bp + ks * 32);
    bl[ks] = *(const bf16x8*)(bq + ks * 32);
  }

#pragma unroll
  for (int c = 0; c < MTW; c++) {
    int mt = (w / NSTRIP) * MTW + c;
    f32x4 acc = {0.f, 0.f, 0.f, 0.f};
    const unsigned short* ap = &Ahi[(mt * 16 + r16) * KP + quad * 8];
    const unsigned short* aq = &Alo[(mt * 16 + r16) * KP + quad * 8];
#pragma unroll
    for (int ks = 0; ks < KSTEPS; ks++) {
      bf16x8 ah = *(const bf16x8*)(ap + ks * 32);
      bf16x8 al = *(const bf16x8*)(aq + ks * 32);
      acc = __builtin_amdgcn_mfma_f32_16x16x32_bf16(ah, bh[ks], acc, 0, 0, 0);
      acc = __builtin_amdgcn_mfma_f32_16x16x32_bf16(ah, bl[ks], acc, 0, 0, 0);
      acc = __builtin_amdgcn_mfma_f32_16x16x32_bf16(al, bh[ks], acc, 0, 0, 0);
    }
    int gn  = node0 + mt * 16 + quad * 4;
    int col = strip * 16 + r16;
#pragma unroll
    for (int r = 0; r < 4; r++) {
      if (gn + r < N_NODES)
        Y16[(size_t)(gn + r) * M + col] = f2bf(acc[r] * dinv[gn + r]);
    }
  }
}

// ---------------- aggregation (ushort8 gathers; table premultiplied by dinv) -------
// out[d] = dinv[d] * (sum_{s in N(d)} h'[s] + h'[d]) + b,  h' = h * dinv[src].

template<int FEAT, bool RELU>
__global__ __launch_bounds__(256) void k_aggregate(const unsigned short* __restrict__ H16,
                            const int* __restrict__ beg,
                            const int* __restrict__ cnt,
                            const int* __restrict__ csr4,
                            const float* __restrict__ dinv, const float* __restrict__ bias,
                            float* __restrict__ OUT) {
  constexpr int LPE    = FEAT / 8;   // lanes per edge (8 or 4)
  constexpr int GROUPS = 64 / LPE;   // edges per wave gather (8 or 16)

  int node = blockIdx.x * 4 + (threadIdx.x >> 6);
  int lane = threadIdx.x & 63;
  if (node >= N_NODES) return;
  int bg = beg[node], end = bg + cnt[node];
  int g  = lane / LPE;               // which edge of the batch
  int f8 = lane % LPE;               // which feature octet

  float a0=0.f,a1=0.f,a2=0.f,a3=0.f,a4=0.f,a5=0.f,a6=0.f,a7=0.f;

  for (int p = bg; p < end; p += 2 * GROUPS) {
    int q0 = p + g, q1 = p + GROUPS + g;
    int s0 = (q0 < end) ? csr4[q0] : node;
    int s1 = (q1 < end) ? csr4[q1] : node;
    float m0 = (q0 < end) ? 1.f : 0.f;
    float m1 = (q1 < end) ? 1.f : 0.f;
    u16x8 h0 = *(const u16x8*)(H16 + (size_t)s0 * FEAT + f8 * 8);
    u16x8 h1 = *(const u16x8*)(H16 + (size_t)s1 * FEAT + f8 * 8);
    a0 += bf2f(h0[0]) * m0; a1 += bf2f(h0[1]) * m0;
    a2 += bf2f(h0[2]) * m0; a3 += bf2f(h0[3]) * m0;
    a4 += bf2f(h0[4]) * m0; a5 += bf2f(h0[5]) * m0;
    a6 += bf2f(h0[6]) * m0; a7 += bf2f(h0[7]) * m0;
    a0 += bf2f(h1[0]) * m1; a1 += bf2f(h1[1]) * m1;
    a2 += bf2f(h1[2]) * m1; a3 += bf2f(h1[3]) * m1;
    a4 += bf2f(h1[4]) * m1; a5 += bf2f(h1[5]) * m1;
    a6 += bf2f(h1[6]) * m1; a7 += bf2f(h1[7]) * m1;
  }

  // fold edge-groups together (g lives in the upper lane bits)
#pragma unroll
  for (int off = LPE; off < 64; off <<= 1) {
    a0 += __shfl_xor(a0, off, 64);
    a1 += __shfl_xor(a1, off, 64);
    a2 += __shfl_xor(a2, off, 64);
    a3 += __shfl_xor(a3, off, 64);
    a4 += __shfl_xor(a4, off, 64);
    a5 += __shfl_xor(a5, off, 64);
    a6 += __shfl_xor(a6, off, 64);
    a7 += __shfl_xor(a7, off, 64);
  }

  if (g == 0) {
    float di = dinv[node];
    u16x8 hs = *(const u16x8*)(H16 + (size_t)node * FEAT + f8 * 8);
    float4 bv0 = *(const float4*)(bias + f8 * 8);
    float4 bv1 = *(const float4*)(bias + f8 * 8 + 4);
    a0 = (a0 + bf2f(hs[0])) * di + bv0.x;
    a1 = (a1 + bf2f(hs[1])) * di + bv0.y;
    a2 = (a2 + bf2f(hs[2])) * di + bv0.z;
    a3 = (a3 + bf2f(hs[3])) * di + bv0.w;
    a4 = (a4 + bf2f(hs[4])) * di + bv1.x;
    a5 = (a5 + bf2f(hs[5])) * di + bv1.y;
    a6 = (a6 + bf2f(hs[6])) * di + bv1.z;
    a7 = (a7 + bf2f(hs[7])) * di + bv1.w;
    if (RELU) {
      a0 = fmaxf(a0, 0.f); a1 = fmaxf(a1, 0.f);
      a2 = fmaxf(a2, 0.f); a3 = fmaxf(a3, 0.f);
      a4 = fmaxf(a4, 0.f); a5 = fmaxf(a5, 0.f);
      a6 = fmaxf(a6, 0.f); a7 = fmaxf(a7, 0.f);
    }
    float4 o0; o0.x = a0; o0.y = a1; o0.z = a2; o0.w = a3;
    float4 o1; o1.x = a4; o1.y = a5; o1.z = a6; o1.w = a7;
    *(float4*)(OUT + (size_t)node * FEAT + f8 * 8)     = o0;
    *(float4*)(OUT + (size_t)node * FEAT + f8 * 8 + 4) = o1;
  }
}

// ---------------- decoder: fused 2-stage MFMA ----------------

__global__ __launch_bounds__(256) void k_decoder_mfma(
    const float* __restrict__ Z,
    const unsigned short* __restrict__ B1hi, const unsigned short* __restrict__ B1lo,
    const float* __restrict__ bd1,
    const unsigned short* __restrict__ B2hi, const unsigned short* __restrict__ B2lo,
    const float* __restrict__ bd2, float* __restrict__ RECON) {
  constexpr int KP1 = 40;   // 32+8
  constexpr int KP2 = 72;   // 64+8
  __shared__ __align__(16) unsigned short Azhi[64 * KP1];
  __shared__ __align__(16) unsigned short Azlo[64 * KP1];
  __shared__ __align__(16) unsigned short H3hi[64 * KP2];
  __shared__ __align__(16) unsigned short H3lo[64 * KP2];
  int t = threadIdx.x;
  int node0 = blockIdx.x * 64;

  for (int i = t; i < 512; i += 256) {
    int n = i >> 3, f4 = i & 7;
    float4 v = make_float4(0.f, 0.f, 0.f, 0.f);
    if (node0 + n < N_NODES) v = ((const float4*)(Z + (size_t)(node0 + n) * 32))[f4];
    int base = n * KP1 + f4 * 4;
    float vv[4] = {v.x, v.y, v.z, v.w};
#pragma unroll
    for (int j = 0; j < 4; j++) {
      unsigned short h = f2bf(vv[j]);
      Azhi[base + j] = h;
      Azlo[base + j] = f2bf(vv[j] - bf2f(h));
    }
  }
  __syncthreads();

  int w = t >> 6, lane = t & 63;
  int quad = lane >> 4, r16 = lane & 15;

  {
    int col = w * 16 + r16;
    float bias1 = bd1[col];
    bf16x8 bh = *(const bf16x8*)(B1hi + col * KP1 + quad * 8);
    bf16x8 bl = *(const bf16x8*)(B1lo + col * KP1 + quad * 8);
#pragma unroll
    for (int m = 0; m < 4; m++) {
      bf16x8 ah = *(const bf16x8*)(Azhi + (m * 16 + r16) * KP1 + quad * 8);
      bf16x8 al = *(const bf16x8*)(Azlo + (m * 16 + r16) * KP1 + quad * 8);
      f32x4 acc = {0.f, 0.f, 0.f, 0.f};
      acc = __builtin_amdgcn_mfma_f32_16x16x32_bf16(ah, bh, acc, 0, 0, 0);
      acc = __builtin_amdgcn_mfma_f32_16x16x32_bf16(ah, bl, acc, 0, 0, 0);
      acc = __builtin_amdgcn_mfma_f32_16x16x32_bf16(al, bh, acc, 0, 0, 0);
#pragma unroll
      for (int r = 0; r < 4; r++) {
        int row = m * 16 + quad * 4 + r;
        float hv = fmaxf(acc[r] + bias1, 0.f);
        unsigned short h = f2bf(hv);
        H3hi[row * KP2 + col] = h;
        H3lo[row * KP2 + col] = f2bf(hv - bf2f(h));
      }
    }
  }
  __syncthreads();

#pragma unroll
  for (int sp = 0; sp < 2; sp++) {
    int strip = w + sp * 4;
    int col = strip * 16 + r16;
    float bias2 = bd2[col];
    const unsigned short* b2h = B2hi + col * KP2 + quad * 8;
    const unsigned short* b2l = B2lo + col * KP2 + quad * 8;
    bf16x8 bh0 = *(const bf16x8*)(b2h);
    bf16x8 bh1 = *(const bf16x8*)(b2h + 32);
    bf16x8 bl0 = *(const bf16x8*)(b2l);
    bf16x8 bl1 = *(const bf16x8*)(b2l + 32);
#pragma unroll
    for (int m = 0; m < 4; m++) {
      const unsigned short* ahp = H3hi + (m * 16 + r16) * KP2 + quad * 8;
      const unsigned short* alp = H3lo + (m * 16 + r16) * KP2 + quad * 8;
      bf16x8 ah0 = *(const bf16x8*)(ahp);
      bf16x8 ah1 = *(const bf16x8*)(ahp + 32);
      bf16x8 al0 = *(const bf16x8*)(alp);
      bf16x8 al1 = *(const bf16x8*)(alp + 32);
      f32x4 acc = {0.f, 0.f, 0.f, 0.f};
      acc = __builtin_amdgcn_mfma_f32_16x16x32_bf16(ah0, bh0, acc, 0, 0, 0);
      acc = __builtin_amdgcn_mfma_f32_16x16x32_bf16(ah1, bh1, acc, 0, 0, 0);
      acc = __builtin_amdgcn_mfma_f32_16x16x32_bf16(ah0, bl0, acc, 0, 0, 0);
      acc = __builtin_amdgcn_mfma_f32_16x16x32_bf16(ah1, bl1, acc, 0, 0, 0);
      acc = __builtin_amdgcn_mfma_f32_16x16x32_bf16(al0, bh0, acc, 0, 0, 0);
      acc = __builtin_amdgcn_mfma_f32_16x16x32_bf16(al1, bh1, acc, 0, 0, 0);
#pragma unroll
      for (int r = 0; r < 4; r++) {
        int n = node0 + m * 16 + quad * 4 + r;
        if (n < N_NODES) RECON[(size_t)n * 128 + col] = acc[r] + bias2;
      }
    }
  }
}

// ---------------- launch ----------------

extern "C" void kernel_launch(void* const* d_in, const int* in_sizes, int n_in,
                              void* d_out, int out_size, void* d_ws, size_t ws_size,
                              hipStream_t stream) {
  const float* x    = (const float*)d_in[0];
  const int*   eidx = (const int*)d_in[1];     // int32 per harness contract
  const int*   esrc = eidx;                    // edge_index[0]
  const int*   edst = eidx + N_EDGES;          // edge_index[1]
  const float* W1  = (const float*)d_in[2];
  const float* b1  = (const float*)d_in[3];
  const float* W2  = (const float*)d_in[4];
  const float* b2  = (const float*)d_in[5];
  const float* Wd1 = (const float*)d_in[6];
  const float* bd1 = (const float*)d_in[7];
  const float* Wd2 = (const float*)d_in[8];
  const float* bd2 = (const float*)d_in[9];

  float* recon = (float*)d_out;                                  // [N,128]
  float* z     = (float*)d_out + (size_t)N_NODES * D_INF;        // [N,32]
  // Scratch in the dead recon region (51.2 MB, written only by k_decoder_mfma):
  //   stage [196*10240] int2 @ +0    (16.06 MB) -- binned edges; dead after
  //                                               k_csr, region then reused:
  //   h1_16 [N,64] bf16 @ +0         (12.8 MB)
  //   z1    [N,64] fp32 @ +12.8 MB   (25.6 MB)
  //   h2_16 [N,32] bf16 @ +38.4 MB   ( 6.4 MB)   -> total 44.8 MB < 51.2 MB
  int2*           stage = (int2*)recon;
  unsigned short* h1_16 = (unsigned short*)recon;
  float*          z1    = (float*)((char*)recon + 12800000);
  unsigned short* h2_16 = (unsigned short*)((char*)recon + 38400000);

  char* ws = (char*)d_ws;
  int*   beg    = (int*)(ws + 0);              // 409,600
  int*   cntn   = (int*)(ws + 409600);         // 409,600
  float* dinv   = (float*)(ws + 819200);       // 409,600
  int*   bkcnt  = (int*)(ws + 1228800);        // 1,024
  int*   csr4   = (int*)(ws + 1229824);        // 8,028,160 (196*10240*4)
  unsigned short* w1hi  = (unsigned short*)(ws + 9257984);   // 17,408
  unsigned short* w1lo  = (unsigned short*)(ws + 9275392);   // 17,408
  unsigned short* w2hi  = (unsigned short*)(ws + 9292800);   //  4,608
  unsigned short* w2lo  = (unsigned short*)(ws + 9297408);   //  4,608
  unsigned short* wd1hi = (unsigned short*)(ws + 9302016);   //  5,120
  unsigned short* wd1lo = (unsigned short*)(ws + 9307136);   //  5,120
  unsigned short* wd2hi = (unsigned short*)(ws + 9312256);   // 18,432
  unsigned short* wd2lo = (unsigned short*)(ws + 9330688);   // 18,432
  // total ws use: 9,349,120 B

  k_zerobkt<<<1, 256, 0, stream>>>(bkcnt);
  k_binA<<<ABLOCKS, 256, 0, stream>>>(esrc, edst, bkcnt, stage);
  k_csr<<<NBKT, 512, 0, stream>>>(stage, bkcnt, beg, cntn, dinv, csr4);
  k_prep_w<<<4, 256, 0, stream>>>(W1, W2, Wd1, Wd2, w1hi, w1lo, w2hi, w2lo,
                                  wd1hi, wd1lo, wd2hi, wd2lo);

  // h1' = (x @ W1) * dinv  (bf16 out)  -- overwrites stage (dead after k_csr)
  k_mfma_gemm<64, 128, 64><<<(N_NODES + 63) / 64, 256, 0, stream>>>(x, w1hi, w1lo, dinv, h1_16);
  // z1 = relu(dinv*(sum h1' + self) + b1)  (fp32 out)
  k_aggregate<64, true><<<(N_NODES + 3) / 4, 256, 0, stream>>>(h1_16, beg, cntn, csr4, dinv, b1, z1);
  // h2' = (z1 @ W2) * dinv  (bf16 out)
  k_mfma_gemm<64, 64, 32><<<(N_NODES + 63) / 64, 256, 0, stream>>>(z1, w2hi, w2lo, dinv, h2_16);
  // z = dinv*(sum h2' + self) + b2  (latent output, fp32)
  k_aggregate<32, false><<<(N_NODES + 3) / 4, 256, 0, stream>>>(h2_16, beg, cntn, csr4, dinv, b2, z);
  // recon = relu(z@Wd1+bd1) @ Wd2 + bd2
  k_decoder_mfma<<<(N_NODES + 63) / 64, 256, 0, stream>>>(z, wd1hi, wd1lo, bd1,
                                                          wd2hi, wd2lo, bd2, recon);
}